// Round 6
// baseline (271.663 us; speedup 1.0000x reference)
//
#include <hip/hip_runtime.h>
#include <stdint.h>

typedef short bf16x8 __attribute__((ext_vector_type(8)));
typedef float f32x4  __attribute__((ext_vector_type(4)));

#define LOG2E_F 1.4426950408889634f
// 0.125 * log2(e): folded into Q so exp2 args need no multiply
#define QSCALE_F 0.1803368801111204f

__device__ __forceinline__ unsigned short f2bf(float f) {
    unsigned int u = __float_as_uint(f);
    return (unsigned short)((u + 0x7FFFu + ((u >> 16) & 1u)) >> 16);
}

// fast pack for non-negative, non-NaN values (round-half-up)
__device__ __forceinline__ unsigned short f2bfu(float f) {
    return (unsigned short)((__float_as_uint(f) + 0x8000u) >> 16);
}

__device__ __forceinline__ uint4 pack8(float4 a, float4 b) {
    union { unsigned short us[8]; uint4 v; } p;
    p.us[0] = f2bf(a.x); p.us[1] = f2bf(a.y); p.us[2] = f2bf(a.z); p.us[3] = f2bf(a.w);
    p.us[4] = f2bf(b.x); p.us[5] = f2bf(b.y); p.us[6] = f2bf(b.z); p.us[7] = f2bf(b.w);
    return p.v;
}

// ===================== 0. f32 -> bf16 convert (X, in_proj_w, out_w) =====================
__global__ __launch_bounds__(256)
void cvt_kernel(const float* __restrict__ q, const float* __restrict__ k,
                const float* __restrict__ v, const float* __restrict__ w,
                const float* __restrict__ ow,
                uint4* __restrict__ Xb, uint4* __restrict__ Wb, uint4* __restrict__ OWb)
{
    const unsigned g = blockIdx.x * 256 + threadIdx.x;   // 0 .. 2097151
    const float* src;
    uint4* dst;
    if (g < 1572864u) {
        dst = Xb + g;
        if (g < 524288u)        src = q + (size_t)g * 8;
        else if (g < 1048576u)  src = k + (size_t)(g - 524288u) * 8;
        else                    src = v + (size_t)(g - 1048576u) * 8;
    } else if (g < 1966080u) {
        src = w + (size_t)(g - 1572864u) * 8;
        dst = Wb + (g - 1572864u);
    } else {
        src = ow + (size_t)(g - 1966080u) * 8;
        dst = OWb + (g - 1966080u);
    }
    float4 a = *(const float4*)src;
    float4 b = *(const float4*)(src + 4);
    *dst = pack8(a, b);
}

// ===================== 1. QKV projection GEMM (bf16 in, BK=64, prefetch) =====================
__global__ __launch_bounds__(256)
void qkv_proj_kernel(const unsigned short* __restrict__ Xb, const unsigned short* __restrict__ Wb,
                     const float* __restrict__ bias,
                     unsigned short* __restrict__ Qb, unsigned short* __restrict__ Kb,
                     unsigned short* __restrict__ Vtb)
{
    const int z = blockIdx.z;
    const int j   = blockIdx.x;           // 0..255
    const int xcd = j & 7, idx = j >> 3;  // idx 0..31
    const int row0 = ((xcd << 2) + (idx >> 3)) * 128;
    const int col0 = (idx & 7) * 128;
    const int wofs = z << 10;

    const unsigned short* A = Xb + (size_t)z * 4194304;
    const unsigned short* B = Wb;

    __shared__ __align__(16) unsigned short As[128 * 72];
    __shared__ __align__(16) unsigned short Bs[128 * 72];

    const int tid  = threadIdx.x;
    const int lane = tid & 63;
    const int wv   = tid >> 6;
    const int wr   = wv >> 1, wc = wv & 1;

    const f32x4 zero4 = {0.f, 0.f, 0.f, 0.f};
    f32x4 acc[4][4];
#pragma unroll
    for (int m = 0; m < 4; ++m)
#pragma unroll
        for (int n = 0; n < 4; ++n) acc[m][n] = zero4;

    const int srow = tid >> 1;
    const int scol = (tid & 1) << 5;
    const int arow = wr * 64 + (lane & 15);
    const int brow = wc * 64 + (lane & 15);
    const int kof  = (lane >> 4) << 3;

    const unsigned short* pa = A + (size_t)(row0 + srow) * 1024 + scol;
    const unsigned short* pb = B + (size_t)(wofs + col0 + srow) * 1024 + scol;
    uint4 ra0 = *(const uint4*)(pa + 0),  ra1 = *(const uint4*)(pa + 8);
    uint4 ra2 = *(const uint4*)(pa + 16), ra3 = *(const uint4*)(pa + 24);
    uint4 rb0 = *(const uint4*)(pb + 0),  rb1 = *(const uint4*)(pb + 8);
    uint4 rb2 = *(const uint4*)(pb + 16), rb3 = *(const uint4*)(pb + 24);

    for (int k0 = 0; k0 < 1024; k0 += 64) {
        __syncthreads();
        *(uint4*)&As[srow * 72 + scol]      = ra0;
        *(uint4*)&As[srow * 72 + scol + 8]  = ra1;
        *(uint4*)&As[srow * 72 + scol + 16] = ra2;
        *(uint4*)&As[srow * 72 + scol + 24] = ra3;
        *(uint4*)&Bs[srow * 72 + scol]      = rb0;
        *(uint4*)&Bs[srow * 72 + scol + 8]  = rb1;
        *(uint4*)&Bs[srow * 72 + scol + 16] = rb2;
        *(uint4*)&Bs[srow * 72 + scol + 24] = rb3;
        __syncthreads();

        if (k0 < 960) {
            pa = A + (size_t)(row0 + srow) * 1024 + k0 + 64 + scol;
            pb = B + (size_t)(wofs + col0 + srow) * 1024 + k0 + 64 + scol;
            ra0 = *(const uint4*)(pa + 0);  ra1 = *(const uint4*)(pa + 8);
            ra2 = *(const uint4*)(pa + 16); ra3 = *(const uint4*)(pa + 24);
            rb0 = *(const uint4*)(pb + 0);  rb1 = *(const uint4*)(pb + 8);
            rb2 = *(const uint4*)(pb + 16); rb3 = *(const uint4*)(pb + 24);
        }

#pragma unroll
        for (int kk = 0; kk < 2; ++kk) {
            bf16x8 af[4], bfr[4];
#pragma unroll
            for (int m = 0; m < 4; ++m)
                af[m] = *(const bf16x8*)&As[(arow + m * 16) * 72 + kk * 32 + kof];
#pragma unroll
            for (int n = 0; n < 4; ++n)
                bfr[n] = *(const bf16x8*)&Bs[(brow + n * 16) * 72 + kk * 32 + kof];
#pragma unroll
            for (int m = 0; m < 4; ++m)
#pragma unroll
                for (int n = 0; n < 4; ++n)
                    acc[m][n] = __builtin_amdgcn_mfma_f32_16x16x32_bf16(af[m], bfr[n], acc[m][n], 0, 0, 0);
        }
    }

    const int ccol = lane & 15;
    const int crow = (lane >> 4) << 2;
#pragma unroll
    for (int n = 0; n < 4; ++n) {
        const int gc   = col0 + wc * 64 + n * 16 + ccol;
        const float bv = bias[wofs + gc];
        const int head = gc >> 6, d = gc & 63;
#pragma unroll
        for (int m = 0; m < 4; ++m) {
#pragma unroll
            for (int r = 0; r < 4; ++r) {
                const int gr = row0 + wr * 64 + m * 16 + crow + r;
                const int t  = gr >> 2, b = gr & 3;
                const int bh = (b << 4) + head;
                float vv = acc[m][n][r] + bv;
                if (z == 0)      Qb [((size_t)bh << 16) + ((size_t)t << 6) + d]  = f2bf(vv * QSCALE_F);
                else if (z == 1) Kb [((size_t)bh << 16) + ((size_t)t << 6) + d]  = f2bf(vv);
                else             Vtb[((size_t)bh << 16) + ((size_t)d << 10) + t] = f2bf(vv);
            }
        }
    }
}

// ===================== 2. flash attention (fixed-shift softmax, barrier-free, L2-direct K/V) =====================
// K/V fragments read directly from global (L2-resident: 256 KB/bh, 8 bh per XCD).
// Ps is wave-local LDS; no __syncthreads anywhere -> waves free-run.
__global__ __launch_bounds__(256)
void flash_kernel(const unsigned short* __restrict__ Qb, const unsigned short* __restrict__ Kb,
                  const unsigned short* __restrict__ Vtb, const float* __restrict__ attn_mask,
                  const int* __restrict__ padmask,
                  float* __restrict__ rl_buf, unsigned short* __restrict__ attn_out)
{
    const int j   = blockIdx.x;              // 0..1023
    const int xcd = j & 7, idx = j >> 3;     // idx 0..127
    const int bh  = xcd * 8 + (idx >> 4);
    const int t0  = (idx & 15) << 6;
    const int b   = bh >> 4, h = bh & 15;

    __shared__ __align__(16) unsigned short Ps[64 * 72];  // wave-local 16-row slabs

    const int tid  = threadIdx.x;
    const int lane = tid & 63;
    const int wv   = tid >> 6;
    const int kof  = (lane >> 4) << 3;
    const int c16  = lane & 15;

    const unsigned short* Qbase = Qb  + ((size_t)bh << 16);
    const unsigned short* Kbase = Kb  + ((size_t)bh << 16);
    const unsigned short* Vbase = Vtb + ((size_t)bh << 16);

    bf16x8 qf[2];
#pragma unroll
    for (int kk = 0; kk < 2; ++kk)
        qf[kk] = *(const bf16x8*)(Qbase + ((size_t)(t0 + wv * 16 + c16) << 6) + kk * 32 + kof);

    const bf16x8 ones = {16256, 16256, 16256, 16256, 16256, 16256, 16256, 16256};

    const f32x4 zero4 = {0.f, 0.f, 0.f, 0.f};
    f32x4 acco[4];
#pragma unroll
    for (int nd = 0; nd < 4; ++nd) acco[nd] = zero4;
    f32x4 acc_l = zero4;

    const int rbase = wv * 16 + ((lane >> 4) << 2);
    const int tr    = t0 + rbase;

    for (int s0 = 0; s0 < 1024; s0 += 64) {
        // QK^T: K fragments straight from global (L2-hot)
        f32x4 accs[4];
#pragma unroll
        for (int n = 0; n < 4; ++n) accs[n] = zero4;
        __builtin_amdgcn_s_setprio(1);
#pragma unroll
        for (int n = 0; n < 4; ++n) {
            const unsigned short* kr = Kbase + ((size_t)(s0 + n * 16 + c16) << 6) + kof;
            bf16x8 kf0 = *(const bf16x8*)(kr);
            bf16x8 kf1 = *(const bf16x8*)(kr + 32);
            accs[n] = __builtin_amdgcn_mfma_f32_16x16x32_bf16(qf[0], kf0, accs[n], 0, 0, 0);
            accs[n] = __builtin_amdgcn_mfma_f32_16x16x32_bf16(qf[1], kf1, accs[n], 0, 0, 0);
        }
        __builtin_amdgcn_s_setprio(0);

        int pad_s[4];
#pragma unroll
        for (int n = 0; n < 4; ++n)
            pad_s[n] = padmask[(b << 10) + s0 + n * 16 + c16];

#pragma unroll
        for (int r = 0; r < 4; ++r) {
            const float* mp = attn_mask + (size_t)(tr + r) * 1024 + s0 + c16;
            float x0 = fmaf(mp[ 0], LOG2E_F, accs[0][r]);
            float x1 = fmaf(mp[16], LOG2E_F, accs[1][r]);
            float x2 = fmaf(mp[32], LOG2E_F, accs[2][r]);
            float x3 = fmaf(mp[48], LOG2E_F, accs[3][r]);
            if (pad_s[0]) x0 = -1e30f;
            if (pad_s[1]) x1 = -1e30f;
            if (pad_s[2]) x2 = -1e30f;
            if (pad_s[3]) x3 = -1e30f;
            const float p0 = __builtin_amdgcn_exp2f(x0);
            const float p1 = __builtin_amdgcn_exp2f(x1);
            const float p2 = __builtin_amdgcn_exp2f(x2);
            const float p3 = __builtin_amdgcn_exp2f(x3);
            const int prow = rbase + r;
            Ps[prow * 72 +  0 + c16] = f2bfu(p0);
            Ps[prow * 72 + 16 + c16] = f2bfu(p1);
            Ps[prow * 72 + 32 + c16] = f2bfu(p2);
            Ps[prow * 72 + 48 + c16] = f2bfu(p3);
        }
        // no barrier: Ps rows are wave-local (lgkmcnt orders write->read)

        // PV + row-sum: V fragments straight from global (L2-hot)
        __builtin_amdgcn_s_setprio(1);
#pragma unroll
        for (int kk2 = 0; kk2 < 2; ++kk2) {
            bf16x8 pf = *(const bf16x8*)&Ps[(wv * 16 + c16) * 72 + kk2 * 32 + kof];
#pragma unroll
            for (int nd = 0; nd < 4; ++nd) {
                bf16x8 vf = *(const bf16x8*)(Vbase + ((size_t)(nd * 16 + c16) << 10) + s0 + kk2 * 32 + kof);
                acco[nd] = __builtin_amdgcn_mfma_f32_16x16x32_bf16(pf, vf, acco[nd], 0, 0, 0);
            }
            acc_l = __builtin_amdgcn_mfma_f32_16x16x32_bf16(pf, ones, acc_l, 0, 0, 0);
        }
        __builtin_amdgcn_s_setprio(0);
    }

#pragma unroll
    for (int r = 0; r < 4; ++r) {
        const int t = t0 + rbase + r;
        const float rl = 1.0f / acc_l[r];
        if (c16 == 0)
            rl_buf[(bh << 10) + t] = rl;
#pragma unroll
        for (int nd = 0; nd < 4; ++nd) {
            const int d = nd * 16 + c16;
            attn_out[((size_t)t * 4 + b) * 1024 + h * 64 + d] = f2bf(acco[nd][r] * rl);
        }
    }
}

// ===================== 3. weights_avg (recompute, barrier-free, L2-direct Q/K) =====================
__global__ __launch_bounds__(256)
void wavg_kernel(const unsigned short* __restrict__ Qb, const unsigned short* __restrict__ Kb,
                 const float* __restrict__ attn_mask, const int* __restrict__ padmask,
                 const float* __restrict__ rl_buf, float* __restrict__ wout)
{
    const int j   = blockIdx.x;              // 0..1023
    const int xcd = j & 7;
    const int b   = xcd >> 1;
    const int rr  = ((j >> 3) << 1) + (xcd & 1);  // 0..255
    const int t0  = (rr >> 4) << 6;
    const int s0  = (rr & 15) << 6;

    const int tid  = threadIdx.x;
    const int lane = tid & 63;
    const int wv   = tid >> 6;
    const int wr   = wv >> 1, wc = wv & 1;
    const int kof  = (lane >> 4) << 3;
    const int c16  = lane & 15;

    const int t_base = t0 + wr * 32 + ((lane >> 4) << 2);
    const int s_base = s0 + wc * 32 + c16;

    int pad2[2];
#pragma unroll
    for (int nn = 0; nn < 2; ++nn) pad2[nn] = padmask[(b << 10) + s_base + nn * 16];

    float maskv[2][2][4];
#pragma unroll
    for (int mm = 0; mm < 2; ++mm)
#pragma unroll
        for (int r = 0; r < 4; ++r)
#pragma unroll
            for (int nn = 0; nn < 2; ++nn)
                maskv[mm][nn][r] = attn_mask[(size_t)(t_base + mm * 16 + r) * 1024 + s_base + nn * 16] * LOG2E_F;

    float wsum[2][2][4];
#pragma unroll
    for (int mm = 0; mm < 2; ++mm)
#pragma unroll
        for (int nn = 0; nn < 2; ++nn)
#pragma unroll
            for (int r = 0; r < 4; ++r) wsum[mm][nn][r] = 0.f;

    const f32x4 zero4 = {0.f, 0.f, 0.f, 0.f};

    for (int h = 0; h < 16; ++h) {
        const int bh = (b << 4) + h;
        const unsigned short* Qh = Qb + ((size_t)bh << 16);
        const unsigned short* Kh = Kb + ((size_t)bh << 16);

        float rlv[2][4];
#pragma unroll
        for (int mm = 0; mm < 2; ++mm)
#pragma unroll
            for (int r = 0; r < 4; ++r)
                rlv[mm][r] = rl_buf[(bh << 10) + t_base + mm * 16 + r];

        f32x4 accs[2][2];
#pragma unroll
        for (int mm = 0; mm < 2; ++mm)
#pragma unroll
            for (int nn = 0; nn < 2; ++nn) accs[mm][nn] = zero4;

        __builtin_amdgcn_s_setprio(1);
#pragma unroll
        for (int nn = 0; nn < 2; ++nn) {
            const unsigned short* kr = Kh + ((size_t)(s0 + wc * 32 + nn * 16 + c16) << 6) + kof;
            bf16x8 kf0 = *(const bf16x8*)(kr);
            bf16x8 kf1 = *(const bf16x8*)(kr + 32);
#pragma unroll
            for (int mm = 0; mm < 2; ++mm) {
                const unsigned short* qr = Qh + ((size_t)(t0 + wr * 32 + mm * 16 + c16) << 6) + kof;
                bf16x8 qf0 = *(const bf16x8*)(qr);
                bf16x8 qf1 = *(const bf16x8*)(qr + 32);
                accs[mm][nn] = __builtin_amdgcn_mfma_f32_16x16x32_bf16(qf0, kf0, accs[mm][nn], 0, 0, 0);
                accs[mm][nn] = __builtin_amdgcn_mfma_f32_16x16x32_bf16(qf1, kf1, accs[mm][nn], 0, 0, 0);
            }
        }
        __builtin_amdgcn_s_setprio(0);

#pragma unroll
        for (int mm = 0; mm < 2; ++mm)
#pragma unroll
            for (int nn = 0; nn < 2; ++nn)
#pragma unroll
                for (int r = 0; r < 4; ++r)
                    if (!pad2[nn]) {
                        float x = accs[mm][nn][r] + maskv[mm][nn][r];
                        wsum[mm][nn][r] += __builtin_amdgcn_exp2f(x) * rlv[mm][r];
                    }
    }

#pragma unroll
    for (int mm = 0; mm < 2; ++mm)
#pragma unroll
        for (int nn = 0; nn < 2; ++nn)
#pragma unroll
            for (int r = 0; r < 4; ++r)
                wout[((size_t)b << 20) + (size_t)(t_base + mm * 16 + r) * 1024 + s_base + nn * 16]
                    = wsum[mm][nn][r] * 0.0625f;
}

// ===================== 4. out projection GEMM (bf16 A & W, BK=64, prefetch) =====================
__global__ __launch_bounds__(256)
void out_proj_kernel(const unsigned short* __restrict__ A, const unsigned short* __restrict__ Wb,
                     const float* __restrict__ bias, float* __restrict__ out)
{
    const int j   = blockIdx.x;           // 0..255
    const int xcd = j & 7, idx = j >> 3;
    const int row0 = ((xcd << 2) + (idx >> 3)) * 128;
    const int col0 = (idx & 7) * 128;

    __shared__ __align__(16) unsigned short As[128 * 72];
    __shared__ __align__(16) unsigned short Bs[128 * 72];

    const int tid  = threadIdx.x;
    const int lane = tid & 63;
    const int wv   = tid >> 6;
    const int wr   = wv >> 1, wc = wv & 1;

    const f32x4 zero4 = {0.f, 0.f, 0.f, 0.f};
    f32x4 acc[4][4];
#pragma unroll
    for (int m = 0; m < 4; ++m)
#pragma unroll
        for (int n = 0; n < 4; ++n) acc[m][n] = zero4;

    const int srow = tid >> 1;
    const int scol = (tid & 1) << 5;
    const int arow = wr * 64 + (lane & 15);
    const int brow = wc * 64 + (lane & 15);
    const int kof  = (lane >> 4) << 3;

    const unsigned short* pa = A  + (size_t)(row0 + srow) * 1024 + scol;
    const unsigned short* pb = Wb + (size_t)(col0 + srow) * 1024 + scol;
    uint4 ra0 = *(const uint4*)(pa + 0),  ra1 = *(const uint4*)(pa + 8);
    uint4 ra2 = *(const uint4*)(pa + 16), ra3 = *(const uint4*)(pa + 24);
    uint4 rb0 = *(const uint4*)(pb + 0),  rb1 = *(const uint4*)(pb + 8);
    uint4 rb2 = *(const uint4*)(pb + 16), rb3 = *(const uint4*)(pb + 24);

    for (int k0 = 0; k0 < 1024; k0 += 64) {
        __syncthreads();
        *(uint4*)&As[srow * 72 + scol]      = ra0;
        *(uint4*)&As[srow * 72 + scol + 8]  = ra1;
        *(uint4*)&As[srow * 72 + scol + 16] = ra2;
        *(uint4*)&As[srow * 72 + scol + 24] = ra3;
        *(uint4*)&Bs[srow * 72 + scol]      = rb0;
        *(uint4*)&Bs[srow * 72 + scol + 8]  = rb1;
        *(uint4*)&Bs[srow * 72 + scol + 16] = rb2;
        *(uint4*)&Bs[srow * 72 + scol + 24] = rb3;
        __syncthreads();

        if (k0 < 960) {
            pa = A  + (size_t)(row0 + srow) * 1024 + k0 + 64 + scol;
            pb = Wb + (size_t)(col0 + srow) * 1024 + k0 + 64 + scol;
            ra0 = *(const uint4*)(pa + 0);  ra1 = *(const uint4*)(pa + 8);
            ra2 = *(const uint4*)(pa + 16); ra3 = *(const uint4*)(pa + 24);
            rb0 = *(const uint4*)(pb + 0);  rb1 = *(const uint4*)(pb + 8);
            rb2 = *(const uint4*)(pb + 16); rb3 = *(const uint4*)(pb + 24);
        }

#pragma unroll
        for (int kk = 0; kk < 2; ++kk) {
            bf16x8 af[4], bfr[4];
#pragma unroll
            for (int m = 0; m < 4; ++m)
                af[m] = *(const bf16x8*)&As[(arow + m * 16) * 72 + kk * 32 + kof];
#pragma unroll
            for (int n = 0; n < 4; ++n)
                bfr[n] = *(const bf16x8*)&Bs[(brow + n * 16) * 72 + kk * 32 + kof];
#pragma unroll
            for (int m = 0; m < 4; ++m)
#pragma unroll
                for (int n = 0; n < 4; ++n)
                    acc[m][n] = __builtin_amdgcn_mfma_f32_16x16x32_bf16(af[m], bfr[n], acc[m][n], 0, 0, 0);
        }
    }

    const int ccol = lane & 15;
    const int crow = (lane >> 4) << 2;
#pragma unroll
    for (int n = 0; n < 4; ++n) {
        const int gc   = col0 + wc * 64 + n * 16 + ccol;
        const float bv = bias[gc];
#pragma unroll
        for (int m = 0; m < 4; ++m) {
#pragma unroll
            for (int r = 0; r < 4; ++r) {
                const int gr = row0 + wr * 64 + m * 16 + crow + r;
                out[(size_t)gr * 1024 + gc] = acc[m][n][r] + bv;
            }
        }
    }
}

// ===================== host =====================
extern "C" void kernel_launch(void* const* d_in, const int* in_sizes, int n_in,
                              void* d_out, int out_size, void* d_ws, size_t ws_size,
                              hipStream_t stream)
{
    const float* query     = (const float*)d_in[0];
    const float* key       = (const float*)d_in[1];
    const float* value     = (const float*)d_in[2];
    const float* attn_mask = (const float*)d_in[3];
    const int*   padmask   = (const int*)  d_in[4];
    const float* in_proj_w = (const float*)d_in[5];
    const float* in_proj_b = (const float*)d_in[6];
    const float* out_w     = (const float*)d_in[7];
    const float* out_b     = (const float*)d_in[8];

    float* out  = (float*)d_out;
    float* wavg = out + 4194304;

    char* ws = (char*)d_ws;
    unsigned short* Qb     = (unsigned short*)(ws);              // 8 MB  [64][1024][64]
    unsigned short* Kb     = (unsigned short*)(ws + 8388608);    // 8 MB
    unsigned short* Vtb    = (unsigned short*)(ws + 16777216);   // 8 MB  [64][64][1024]
    unsigned short* Xb     = (unsigned short*)(ws + 25165824);   // 24 MB (dead after qkv)
    unsigned short* attn_o = (unsigned short*)(ws + 25165824);   // 8 MB  aliases Xb
    unsigned short* Wb     = (unsigned short*)(ws + 50331648);   // 6 MB
    unsigned short* OWb    = (unsigned short*)(ws + 56623104);   // 2 MB
    float*          rl_buf = (float*)(ws + 58720256);            // 256 KB

    cvt_kernel<<<dim3(8192), 256, 0, stream>>>(query, key, value, in_proj_w, out_w,
                                               (uint4*)Xb, (uint4*)Wb, (uint4*)OWb);
    qkv_proj_kernel<<<dim3(256, 1, 3), 256, 0, stream>>>(Xb, Wb, in_proj_b, Qb, Kb, Vtb);
    flash_kernel<<<dim3(1024), 256, 0, stream>>>(Qb, Kb, Vtb, attn_mask, padmask,
                                                 rl_buf, attn_o);
    wavg_kernel<<<dim3(1024), 256, 0, stream>>>(Qb, Kb, attn_mask, padmask,
                                                rl_buf, wavg);
    out_proj_kernel<<<dim3(256), 256, 0, stream>>>(attn_o, OWb, out_b, out);
}

// Round 7
// 184.010 us; speedup vs baseline: 1.4763x; 1.4763x over previous
//
#include <hip/hip_runtime.h>
#include <stdint.h>

typedef short bf16x8 __attribute__((ext_vector_type(8)));
typedef float f32x4  __attribute__((ext_vector_type(4)));

#define LOG2E_F 1.4426950408889634f
// 0.125 * log2(e): folded into Q so exp2 args need no multiply
#define QSCALE_F 0.1803368801111204f

__device__ __forceinline__ unsigned short f2bf(float f) {
    unsigned int u = __float_as_uint(f);
    return (unsigned short)((u + 0x7FFFu + ((u >> 16) & 1u)) >> 16);
}

// fast pack for non-negative, non-NaN values (round-half-up)
__device__ __forceinline__ unsigned short f2bfu(float f) {
    return (unsigned short)((__float_as_uint(f) + 0x8000u) >> 16);
}

__device__ __forceinline__ uint4 pack8(float4 a, float4 b) {
    union { unsigned short us[8]; uint4 v; } p;
    p.us[0] = f2bf(a.x); p.us[1] = f2bf(a.y); p.us[2] = f2bf(a.z); p.us[3] = f2bf(a.w);
    p.us[4] = f2bf(b.x); p.us[5] = f2bf(b.y); p.us[6] = f2bf(b.z); p.us[7] = f2bf(b.w);
    return p.v;
}

// ===================== 0. f32 -> bf16 convert (X, in_proj_w, out_w) =====================
__global__ __launch_bounds__(256)
void cvt_kernel(const float* __restrict__ q, const float* __restrict__ k,
                const float* __restrict__ v, const float* __restrict__ w,
                const float* __restrict__ ow,
                uint4* __restrict__ Xb, uint4* __restrict__ Wb, uint4* __restrict__ OWb)
{
    const unsigned g = blockIdx.x * 256 + threadIdx.x;   // 0 .. 2097151
    const float* src;
    uint4* dst;
    if (g < 1572864u) {
        dst = Xb + g;
        if (g < 524288u)        src = q + (size_t)g * 8;
        else if (g < 1048576u)  src = k + (size_t)(g - 524288u) * 8;
        else                    src = v + (size_t)(g - 1048576u) * 8;
    } else if (g < 1966080u) {
        src = w + (size_t)(g - 1572864u) * 8;
        dst = Wb + (g - 1572864u);
    } else {
        src = ow + (size_t)(g - 1966080u) * 8;
        dst = OWb + (g - 1966080u);
    }
    float4 a = *(const float4*)src;
    float4 b = *(const float4*)(src + 4);
    *dst = pack8(a, b);
}

// ===================== 1. QKV projection GEMM (bf16 in, BK=64, prefetch) =====================
__global__ __launch_bounds__(256)
void qkv_proj_kernel(const unsigned short* __restrict__ Xb, const unsigned short* __restrict__ Wb,
                     const float* __restrict__ bias,
                     unsigned short* __restrict__ Qb, unsigned short* __restrict__ Kb,
                     unsigned short* __restrict__ Vtb)
{
    const int z = blockIdx.z;
    const int j   = blockIdx.x;           // 0..255
    const int xcd = j & 7, idx = j >> 3;  // idx 0..31
    const int row0 = ((xcd << 2) + (idx >> 3)) * 128;
    const int col0 = (idx & 7) * 128;
    const int wofs = z << 10;

    const unsigned short* A = Xb + (size_t)z * 4194304;
    const unsigned short* B = Wb;

    __shared__ __align__(16) unsigned short As[128 * 72];
    __shared__ __align__(16) unsigned short Bs[128 * 72];

    const int tid  = threadIdx.x;
    const int lane = tid & 63;
    const int wv   = tid >> 6;
    const int wr   = wv >> 1, wc = wv & 1;

    const f32x4 zero4 = {0.f, 0.f, 0.f, 0.f};
    f32x4 acc[4][4];
#pragma unroll
    for (int m = 0; m < 4; ++m)
#pragma unroll
        for (int n = 0; n < 4; ++n) acc[m][n] = zero4;

    const int srow = tid >> 1;
    const int scol = (tid & 1) << 5;
    const int arow = wr * 64 + (lane & 15);
    const int brow = wc * 64 + (lane & 15);
    const int kof  = (lane >> 4) << 3;

    const unsigned short* pa = A + (size_t)(row0 + srow) * 1024 + scol;
    const unsigned short* pb = B + (size_t)(wofs + col0 + srow) * 1024 + scol;
    uint4 ra0 = *(const uint4*)(pa + 0),  ra1 = *(const uint4*)(pa + 8);
    uint4 ra2 = *(const uint4*)(pa + 16), ra3 = *(const uint4*)(pa + 24);
    uint4 rb0 = *(const uint4*)(pb + 0),  rb1 = *(const uint4*)(pb + 8);
    uint4 rb2 = *(const uint4*)(pb + 16), rb3 = *(const uint4*)(pb + 24);

    for (int k0 = 0; k0 < 1024; k0 += 64) {
        __syncthreads();
        *(uint4*)&As[srow * 72 + scol]      = ra0;
        *(uint4*)&As[srow * 72 + scol + 8]  = ra1;
        *(uint4*)&As[srow * 72 + scol + 16] = ra2;
        *(uint4*)&As[srow * 72 + scol + 24] = ra3;
        *(uint4*)&Bs[srow * 72 + scol]      = rb0;
        *(uint4*)&Bs[srow * 72 + scol + 8]  = rb1;
        *(uint4*)&Bs[srow * 72 + scol + 16] = rb2;
        *(uint4*)&Bs[srow * 72 + scol + 24] = rb3;
        __syncthreads();

        if (k0 < 960) {
            pa = A + (size_t)(row0 + srow) * 1024 + k0 + 64 + scol;
            pb = B + (size_t)(wofs + col0 + srow) * 1024 + k0 + 64 + scol;
            ra0 = *(const uint4*)(pa + 0);  ra1 = *(const uint4*)(pa + 8);
            ra2 = *(const uint4*)(pa + 16); ra3 = *(const uint4*)(pa + 24);
            rb0 = *(const uint4*)(pb + 0);  rb1 = *(const uint4*)(pb + 8);
            rb2 = *(const uint4*)(pb + 16); rb3 = *(const uint4*)(pb + 24);
        }

#pragma unroll
        for (int kk = 0; kk < 2; ++kk) {
            bf16x8 af[4], bfr[4];
#pragma unroll
            for (int m = 0; m < 4; ++m)
                af[m] = *(const bf16x8*)&As[(arow + m * 16) * 72 + kk * 32 + kof];
#pragma unroll
            for (int n = 0; n < 4; ++n)
                bfr[n] = *(const bf16x8*)&Bs[(brow + n * 16) * 72 + kk * 32 + kof];
#pragma unroll
            for (int m = 0; m < 4; ++m)
#pragma unroll
                for (int n = 0; n < 4; ++n)
                    acc[m][n] = __builtin_amdgcn_mfma_f32_16x16x32_bf16(af[m], bfr[n], acc[m][n], 0, 0, 0);
        }
    }

    const int ccol = lane & 15;
    const int crow = (lane >> 4) << 2;
#pragma unroll
    for (int n = 0; n < 4; ++n) {
        const int gc   = col0 + wc * 64 + n * 16 + ccol;
        const float bv = bias[wofs + gc];
        const int head = gc >> 6, d = gc & 63;
#pragma unroll
        for (int m = 0; m < 4; ++m) {
#pragma unroll
            for (int r = 0; r < 4; ++r) {
                const int gr = row0 + wr * 64 + m * 16 + crow + r;
                const int t  = gr >> 2, b = gr & 3;
                const int bh = (b << 4) + head;
                float vv = acc[m][n][r] + bv;
                if (z == 0)      Qb [((size_t)bh << 16) + ((size_t)t << 6) + d]  = f2bf(vv * QSCALE_F);
                else if (z == 1) Kb [((size_t)bh << 16) + ((size_t)t << 6) + d]  = f2bf(vv);
                else             Vtb[((size_t)bh << 16) + ((size_t)d << 10) + t] = f2bf(vv);
            }
        }
    }
}

// ===================== 2. flash attention (fixed-shift softmax, s-tile=32, 100% occupancy) =====================
// LDS 14.5 KB -> 8 blocks/CU x 4 waves = 32 waves/CU. Row-sum via ones-MFMA, no shuffles.
__global__ __launch_bounds__(256, 8)
void flash_kernel(const unsigned short* __restrict__ Qb, const unsigned short* __restrict__ Kb,
                  const unsigned short* __restrict__ Vtb, const float* __restrict__ attn_mask,
                  const int* __restrict__ padmask,
                  float* __restrict__ rl_buf, unsigned short* __restrict__ attn_out)
{
    const int j   = blockIdx.x;              // 0..1023
    const int xcd = j & 7, idx = j >> 3;     // idx 0..127
    const int bh  = xcd * 8 + (idx >> 4);
    const int t0  = (idx & 15) << 6;
    const int b   = bh >> 4, h = bh & 15;

    __shared__ __align__(16) unsigned short Ks[32 * 72];  // rows=s(32), cols=d(64)+8 pad
    __shared__ __align__(16) unsigned short Vs[64 * 40];  // rows=d(64), cols=s(32)+8 pad
    __shared__ __align__(16) unsigned short Ps[64 * 40];  // rows=t(64), cols=s(32)+8 pad

    const int tid  = threadIdx.x;
    const int lane = tid & 63;
    const int wv   = tid >> 6;
    const int kof  = (lane >> 4) << 3;
    const int c16  = lane & 15;

    const unsigned short* Qbase = Qb  + ((size_t)bh << 16);
    const unsigned short* Kbase = Kb  + ((size_t)bh << 16);
    const unsigned short* Vbase = Vtb + ((size_t)bh << 16);

    bf16x8 qf[2];
#pragma unroll
    for (int kk = 0; kk < 2; ++kk)
        qf[kk] = *(const bf16x8*)(Qbase + ((size_t)(t0 + wv * 16 + c16) << 6) + kk * 32 + kof);

    const bf16x8 ones = {16256, 16256, 16256, 16256, 16256, 16256, 16256, 16256};

    const f32x4 zero4 = {0.f, 0.f, 0.f, 0.f};
    f32x4 acco[4];
#pragma unroll
    for (int nd = 0; nd < 4; ++nd) acco[nd] = zero4;
    f32x4 acc_l = zero4;

    // staging: K tile 32x64 (16B/thread), V tile 64x32 (16B/thread)
    const int srowK = tid >> 3;             // 0..31
    const int scolK = (tid & 7) << 3;       // 0..56
    const int srowV = tid >> 2;             // 0..63
    const int scolV = (tid & 3) << 3;       // 0..24

    const int rbase = wv * 16 + ((lane >> 4) << 2);
    const int tr    = t0 + rbase;

    // prologue: load tile 0 into regs
    uint4 kreg = *(const uint4*)(Kbase + ((size_t)srowK << 6) + scolK);
    uint4 vreg = *(const uint4*)(Vbase + ((size_t)srowV << 10) + scolV);

    for (int it = 0; it < 32; ++it) {
        const int s0 = it << 5;
        __syncthreads();  // previous tile's LDS reads done
        *(uint4*)&Ks[srowK * 72 + scolK] = kreg;
        *(uint4*)&Vs[srowV * 40 + scolV] = vreg;
        __syncthreads();

        if (it < 31) {
            kreg = *(const uint4*)(Kbase + ((size_t)(s0 + 32 + srowK) << 6) + scolK);
            vreg = *(const uint4*)(Vbase + ((size_t)srowV << 10) + (s0 + 32) + scolV);
        }

        // QK^T: 16 t-rows x 32 s-cols per wave
        f32x4 accs[2];
        accs[0] = zero4; accs[1] = zero4;
        __builtin_amdgcn_s_setprio(1);
#pragma unroll
        for (int n = 0; n < 2; ++n) {
            bf16x8 kf0 = *(const bf16x8*)&Ks[(n * 16 + c16) * 72 + kof];
            bf16x8 kf1 = *(const bf16x8*)&Ks[(n * 16 + c16) * 72 + 32 + kof];
            accs[n] = __builtin_amdgcn_mfma_f32_16x16x32_bf16(qf[0], kf0, accs[n], 0, 0, 0);
            accs[n] = __builtin_amdgcn_mfma_f32_16x16x32_bf16(qf[1], kf1, accs[n], 0, 0, 0);
        }
        __builtin_amdgcn_s_setprio(0);

        int pad_s0 = padmask[(b << 10) + s0 + c16];
        int pad_s1 = padmask[(b << 10) + s0 + 16 + c16];

#pragma unroll
        for (int r = 0; r < 4; ++r) {
            const float* mp = attn_mask + (size_t)(tr + r) * 1024 + s0 + c16;
            float x0 = fmaf(mp[ 0], LOG2E_F, accs[0][r]);
            float x1 = fmaf(mp[16], LOG2E_F, accs[1][r]);
            if (pad_s0) x0 = -1e30f;
            if (pad_s1) x1 = -1e30f;
            const float p0 = __builtin_amdgcn_exp2f(x0);
            const float p1 = __builtin_amdgcn_exp2f(x1);
            const int prow = rbase + r;
            Ps[prow * 40 +  0 + c16] = f2bfu(p0);
            Ps[prow * 40 + 16 + c16] = f2bfu(p1);
        }
        // no barrier: Ps rows are wave-local (lgkmcnt orders write->read)

        // PV + row-sum (K-dim = 32 -> single MFMA chain)
        __builtin_amdgcn_s_setprio(1);
        {
            bf16x8 pf = *(const bf16x8*)&Ps[(wv * 16 + c16) * 40 + kof];
#pragma unroll
            for (int nd = 0; nd < 4; ++nd) {
                bf16x8 vf = *(const bf16x8*)&Vs[(nd * 16 + c16) * 40 + kof];
                acco[nd] = __builtin_amdgcn_mfma_f32_16x16x32_bf16(pf, vf, acco[nd], 0, 0, 0);
            }
            acc_l = __builtin_amdgcn_mfma_f32_16x16x32_bf16(pf, ones, acc_l, 0, 0, 0);
        }
        __builtin_amdgcn_s_setprio(0);
    }

#pragma unroll
    for (int r = 0; r < 4; ++r) {
        const int t = t0 + rbase + r;
        const float rl = 1.0f / acc_l[r];
        if (c16 == 0)
            rl_buf[(bh << 10) + t] = rl;
#pragma unroll
        for (int nd = 0; nd < 4; ++nd) {
            const int d = nd * 16 + c16;
            attn_out[((size_t)t * 4 + b) * 1024 + h * 64 + d] = f2bf(acco[nd][r] * rl);
        }
    }
}

// ===================== 3. weights_avg (recompute scores, all heads) =====================
__global__ __launch_bounds__(256)
void wavg_kernel(const unsigned short* __restrict__ Qb, const unsigned short* __restrict__ Kb,
                 const float* __restrict__ attn_mask, const int* __restrict__ padmask,
                 const float* __restrict__ rl_buf, float* __restrict__ wout)
{
    const int j   = blockIdx.x;              // 0..1023
    const int xcd = j & 7;
    const int b   = xcd >> 1;
    const int rr  = ((j >> 3) << 1) + (xcd & 1);  // 0..255
    const int t0  = (rr >> 4) << 6;
    const int s0  = (rr & 15) << 6;

    __shared__ __align__(16) unsigned short Qs[64 * 72];
    __shared__ __align__(16) unsigned short Ks2[64 * 72];

    const int tid  = threadIdx.x;
    const int lane = tid & 63;
    const int wv   = tid >> 6;
    const int wr   = wv >> 1, wc = wv & 1;
    const int kof  = (lane >> 4) << 3;
    const int srow_st = tid >> 2;
    const int scol_st = (tid & 3) << 4;

    const int t_base = t0 + wr * 32 + ((lane >> 4) << 2);
    const int s_base = s0 + wc * 32 + (lane & 15);

    int pad2[2];
#pragma unroll
    for (int nn = 0; nn < 2; ++nn) pad2[nn] = padmask[(b << 10) + s_base + nn * 16];

    float maskv[2][2][4];
#pragma unroll
    for (int mm = 0; mm < 2; ++mm)
#pragma unroll
        for (int r = 0; r < 4; ++r)
#pragma unroll
            for (int nn = 0; nn < 2; ++nn)
                maskv[mm][nn][r] = attn_mask[(size_t)(t_base + mm * 16 + r) * 1024 + s_base + nn * 16] * LOG2E_F;

    float wsum[2][2][4];
#pragma unroll
    for (int mm = 0; mm < 2; ++mm)
#pragma unroll
        for (int nn = 0; nn < 2; ++nn)
#pragma unroll
            for (int r = 0; r < 4; ++r) wsum[mm][nn][r] = 0.f;

    for (int h = 0; h < 16; ++h) {
        const int bh = (b << 4) + h;
        __syncthreads();
        {
            const unsigned short* qp = Qb + ((size_t)bh << 16) + ((size_t)(t0 + srow_st) << 6) + scol_st;
            *(uint4*)&Qs[srow_st * 72 + scol_st]     = *(const uint4*)qp;
            *(uint4*)&Qs[srow_st * 72 + scol_st + 8] = *(const uint4*)(qp + 8);
            const unsigned short* kp = Kb + ((size_t)bh << 16) + ((size_t)(s0 + srow_st) << 6) + scol_st;
            *(uint4*)&Ks2[srow_st * 72 + scol_st]     = *(const uint4*)kp;
            *(uint4*)&Ks2[srow_st * 72 + scol_st + 8] = *(const uint4*)(kp + 8);
        }
        __syncthreads();

        float rlv[2][4];
#pragma unroll
        for (int mm = 0; mm < 2; ++mm)
#pragma unroll
            for (int r = 0; r < 4; ++r)
                rlv[mm][r] = rl_buf[(bh << 10) + t_base + mm * 16 + r];

        const f32x4 zero4 = {0.f, 0.f, 0.f, 0.f};
        f32x4 accs[2][2];
#pragma unroll
        for (int mm = 0; mm < 2; ++mm)
#pragma unroll
            for (int nn = 0; nn < 2; ++nn) accs[mm][nn] = zero4;
#pragma unroll
        for (int nn = 0; nn < 2; ++nn) {
            bf16x8 kf0 = *(const bf16x8*)&Ks2[(wc * 32 + nn * 16 + (lane & 15)) * 72 + kof];
            bf16x8 kf1 = *(const bf16x8*)&Ks2[(wc * 32 + nn * 16 + (lane & 15)) * 72 + 32 + kof];
#pragma unroll
            for (int mm = 0; mm < 2; ++mm) {
                bf16x8 qf0 = *(const bf16x8*)&Qs[(wr * 32 + mm * 16 + (lane & 15)) * 72 + kof];
                bf16x8 qf1 = *(const bf16x8*)&Qs[(wr * 32 + mm * 16 + (lane & 15)) * 72 + 32 + kof];
                accs[mm][nn] = __builtin_amdgcn_mfma_f32_16x16x32_bf16(qf0, kf0, accs[mm][nn], 0, 0, 0);
                accs[mm][nn] = __builtin_amdgcn_mfma_f32_16x16x32_bf16(qf1, kf1, accs[mm][nn], 0, 0, 0);
            }
        }
#pragma unroll
        for (int mm = 0; mm < 2; ++mm)
#pragma unroll
            for (int nn = 0; nn < 2; ++nn)
#pragma unroll
                for (int r = 0; r < 4; ++r)
                    if (!pad2[nn]) {
                        float x = accs[mm][nn][r] + maskv[mm][nn][r];
                        wsum[mm][nn][r] += __builtin_amdgcn_exp2f(x) * rlv[mm][r];
                    }
    }

#pragma unroll
    for (int mm = 0; mm < 2; ++mm)
#pragma unroll
        for (int nn = 0; nn < 2; ++nn)
#pragma unroll
            for (int r = 0; r < 4; ++r)
                wout[((size_t)b << 20) + (size_t)(t_base + mm * 16 + r) * 1024 + s_base + nn * 16]
                    = wsum[mm][nn][r] * 0.0625f;
}

// ===================== 4. out projection GEMM (bf16 A & W, BK=64, prefetch) =====================
__global__ __launch_bounds__(256)
void out_proj_kernel(const unsigned short* __restrict__ A, const unsigned short* __restrict__ Wb,
                     const float* __restrict__ bias, float* __restrict__ out)
{
    const int j   = blockIdx.x;           // 0..255
    const int xcd = j & 7, idx = j >> 3;
    const int row0 = ((xcd << 2) + (idx >> 3)) * 128;
    const int col0 = (idx & 7) * 128;

    __shared__ __align__(16) unsigned short As[128 * 72];
    __shared__ __align__(16) unsigned short Bs[128 * 72];

    const int tid  = threadIdx.x;
    const int lane = tid & 63;
    const int wv   = tid >> 6;
    const int wr   = wv >> 1, wc = wv & 1;

    const f32x4 zero4 = {0.f, 0.f, 0.f, 0.f};
    f32x4 acc[4][4];
#pragma unroll
    for (int m = 0; m < 4; ++m)
#pragma unroll
        for (int n = 0; n < 4; ++n) acc[m][n] = zero4;

    const int srow = tid >> 1;
    const int scol = (tid & 1) << 5;
    const int arow = wr * 64 + (lane & 15);
    const int brow = wc * 64 + (lane & 15);
    const int kof  = (lane >> 4) << 3;

    const unsigned short* pa = A  + (size_t)(row0 + srow) * 1024 + scol;
    const unsigned short* pb = Wb + (size_t)(col0 + srow) * 1024 + scol;
    uint4 ra0 = *(const uint4*)(pa + 0),  ra1 = *(const uint4*)(pa + 8);
    uint4 ra2 = *(const uint4*)(pa + 16), ra3 = *(const uint4*)(pa + 24);
    uint4 rb0 = *(const uint4*)(pb + 0),  rb1 = *(const uint4*)(pb + 8);
    uint4 rb2 = *(const uint4*)(pb + 16), rb3 = *(const uint4*)(pb + 24);

    for (int k0 = 0; k0 < 1024; k0 += 64) {
        __syncthreads();
        *(uint4*)&As[srow * 72 + scol]      = ra0;
        *(uint4*)&As[srow * 72 + scol + 8]  = ra1;
        *(uint4*)&As[srow * 72 + scol + 16] = ra2;
        *(uint4*)&As[srow * 72 + scol + 24] = ra3;
        *(uint4*)&Bs[srow * 72 + scol]      = rb0;
        *(uint4*)&Bs[srow * 72 + scol + 8]  = rb1;
        *(uint4*)&Bs[srow * 72 + scol + 16] = rb2;
        *(uint4*)&Bs[srow * 72 + scol + 24] = rb3;
        __syncthreads();

        if (k0 < 960) {
            pa = A  + (size_t)(row0 + srow) * 1024 + k0 + 64 + scol;
            pb = Wb + (size_t)(col0 + srow) * 1024 + k0 + 64 + scol;
            ra0 = *(const uint4*)(pa + 0);  ra1 = *(const uint4*)(pa + 8);
            ra2 = *(const uint4*)(pa + 16); ra3 = *(const uint4*)(pa + 24);
            rb0 = *(const uint4*)(pb + 0);  rb1 = *(const uint4*)(pb + 8);
            rb2 = *(const uint4*)(pb + 16); rb3 = *(const uint4*)(pb + 24);
        }

#pragma unroll
        for (int kk = 0; kk < 2; ++kk) {
            bf16x8 af[4], bfr[4];
#pragma unroll
            for (int m = 0; m < 4; ++m)
                af[m] = *(const bf16x8*)&As[(arow + m * 16) * 72 + kk * 32 + kof];
#pragma unroll
            for (int n = 0; n < 4; ++n)
                bfr[n] = *(const bf16x8*)&Bs[(brow + n * 16) * 72 + kk * 32 + kof];
#pragma unroll
            for (int m = 0; m < 4; ++m)
#pragma unroll
                for (int n = 0; n < 4; ++n)
                    acc[m][n] = __builtin_amdgcn_mfma_f32_16x16x32_bf16(af[m], bfr[n], acc[m][n], 0, 0, 0);
        }
    }

    const int ccol = lane & 15;
    const int crow = (lane >> 4) << 2;
#pragma unroll
    for (int n = 0; n < 4; ++n) {
        const int gc   = col0 + wc * 64 + n * 16 + ccol;
        const float bv = bias[gc];
#pragma unroll
        for (int m = 0; m < 4; ++m) {
#pragma unroll
            for (int r = 0; r < 4; ++r) {
                const int gr = row0 + wr * 64 + m * 16 + crow + r;
                out[(size_t)gr * 1024 + gc] = acc[m][n][r] + bv;
            }
        }
    }
}

// ===================== host =====================
extern "C" void kernel_launch(void* const* d_in, const int* in_sizes, int n_in,
                              void* d_out, int out_size, void* d_ws, size_t ws_size,
                              hipStream_t stream)
{
    const float* query     = (const float*)d_in[0];
    const float* key       = (const float*)d_in[1];
    const float* value     = (const float*)d_in[2];
    const float* attn_mask = (const float*)d_in[3];
    const int*   padmask   = (const int*)  d_in[4];
    const float* in_proj_w = (const float*)d_in[5];
    const float* in_proj_b = (const float*)d_in[6];
    const float* out_w     = (const float*)d_in[7];
    const float* out_b     = (const float*)d_in[8];

    float* out  = (float*)d_out;
    float* wavg = out + 4194304;

    char* ws = (char*)d_ws;
    unsigned short* Qb     = (unsigned short*)(ws);              // 8 MB  [64][1024][64]
    unsigned short* Kb     = (unsigned short*)(ws + 8388608);    // 8 MB
    unsigned short* Vtb    = (unsigned short*)(ws + 16777216);   // 8 MB  [64][64][1024]
    unsigned short* Xb     = (unsigned short*)(ws + 25165824);   // 24 MB (dead after qkv)
    unsigned short* attn_o = (unsigned short*)(ws + 25165824);   // 8 MB  aliases Xb
    unsigned short* Wb     = (unsigned short*)(ws + 50331648);   // 6 MB
    unsigned short* OWb    = (unsigned short*)(ws + 56623104);   // 2 MB
    float*          rl_buf = (float*)(ws + 58720256);            // 256 KB

    cvt_kernel<<<dim3(8192), 256, 0, stream>>>(query, key, value, in_proj_w, out_w,
                                               (uint4*)Xb, (uint4*)Wb, (uint4*)OWb);
    qkv_proj_kernel<<<dim3(256, 1, 3), 256, 0, stream>>>(Xb, Wb, in_proj_b, Qb, Kb, Vtb);
    flash_kernel<<<dim3(1024), 256, 0, stream>>>(Qb, Kb, Vtb, attn_mask, padmask,
                                                 rl_buf, attn_o);
    wavg_kernel<<<dim3(1024), 256, 0, stream>>>(Qb, Kb, attn_mask, padmask,
                                                rl_buf, wavg);
    out_proj_kernel<<<dim3(256), 256, 0, stream>>>(attn_o, OWb, out_b, out);
}

// Round 8
// 154.311 us; speedup vs baseline: 1.7605x; 1.1925x over previous
//
#include <hip/hip_runtime.h>
#include <stdint.h>

typedef short bf16x8 __attribute__((ext_vector_type(8)));
typedef float f32x4  __attribute__((ext_vector_type(4)));

#define LOG2E_F 1.4426950408889634f
// 0.125 * log2(e): folded into Q so exp2 args need no multiply
#define QSCALE_F 0.1803368801111204f

__device__ __forceinline__ unsigned short f2bf(float f) {
    unsigned int u = __float_as_uint(f);
    return (unsigned short)((u + 0x7FFFu + ((u >> 16) & 1u)) >> 16);
}

// fast pack for non-negative, non-NaN values (round-half-up)
__device__ __forceinline__ unsigned short f2bfu(float f) {
    return (unsigned short)((__float_as_uint(f) + 0x8000u) >> 16);
}

__device__ __forceinline__ uint4 pack8(float4 a, float4 b) {
    union { unsigned short us[8]; uint4 v; } p;
    p.us[0] = f2bf(a.x); p.us[1] = f2bf(a.y); p.us[2] = f2bf(a.z); p.us[3] = f2bf(a.w);
    p.us[4] = f2bf(b.x); p.us[5] = f2bf(b.y); p.us[6] = f2bf(b.z); p.us[7] = f2bf(b.w);
    return p.v;
}

// ===================== 0. f32 -> bf16 convert (X, in_proj_w, out_w) =====================
__global__ __launch_bounds__(256)
void cvt_kernel(const float* __restrict__ q, const float* __restrict__ k,
                const float* __restrict__ v, const float* __restrict__ w,
                const float* __restrict__ ow,
                uint4* __restrict__ Xb, uint4* __restrict__ Wb, uint4* __restrict__ OWb)
{
    const unsigned g = blockIdx.x * 256 + threadIdx.x;   // 0 .. 2097151
    const float* src;
    uint4* dst;
    if (g < 1572864u) {
        dst = Xb + g;
        if (g < 524288u)        src = q + (size_t)g * 8;
        else if (g < 1048576u)  src = k + (size_t)(g - 524288u) * 8;
        else                    src = v + (size_t)(g - 1048576u) * 8;
    } else if (g < 1966080u) {
        src = w + (size_t)(g - 1572864u) * 8;
        dst = Wb + (g - 1572864u);
    } else {
        src = ow + (size_t)(g - 1966080u) * 8;
        dst = OWb + (g - 1966080u);
    }
    float4 a = *(const float4*)src;
    float4 b = *(const float4*)(src + 4);
    *dst = pack8(a, b);
}

// ===================== 1. QKV projection GEMM (bf16 in, BK=64, prefetch) =====================
__global__ __launch_bounds__(256)
void qkv_proj_kernel(const unsigned short* __restrict__ Xb, const unsigned short* __restrict__ Wb,
                     const float* __restrict__ bias,
                     unsigned short* __restrict__ Qb, unsigned short* __restrict__ Kb,
                     unsigned short* __restrict__ Vtb)
{
    const int z = blockIdx.z;
    const int j   = blockIdx.x;           // 0..255
    const int xcd = j & 7, idx = j >> 3;  // idx 0..31
    const int row0 = ((xcd << 2) + (idx >> 3)) * 128;
    const int col0 = (idx & 7) * 128;
    const int wofs = z << 10;

    const unsigned short* A = Xb + (size_t)z * 4194304;
    const unsigned short* B = Wb;

    __shared__ __align__(16) unsigned short As[128 * 72];
    __shared__ __align__(16) unsigned short Bs[128 * 72];

    const int tid  = threadIdx.x;
    const int lane = tid & 63;
    const int wv   = tid >> 6;
    const int wr   = wv >> 1, wc = wv & 1;

    const f32x4 zero4 = {0.f, 0.f, 0.f, 0.f};
    f32x4 acc[4][4];
#pragma unroll
    for (int m = 0; m < 4; ++m)
#pragma unroll
        for (int n = 0; n < 4; ++n) acc[m][n] = zero4;

    const int srow = tid >> 1;
    const int scol = (tid & 1) << 5;
    const int arow = wr * 64 + (lane & 15);
    const int brow = wc * 64 + (lane & 15);
    const int kof  = (lane >> 4) << 3;

    const unsigned short* pa = A + (size_t)(row0 + srow) * 1024 + scol;
    const unsigned short* pb = B + (size_t)(wofs + col0 + srow) * 1024 + scol;
    uint4 ra0 = *(const uint4*)(pa + 0),  ra1 = *(const uint4*)(pa + 8);
    uint4 ra2 = *(const uint4*)(pa + 16), ra3 = *(const uint4*)(pa + 24);
    uint4 rb0 = *(const uint4*)(pb + 0),  rb1 = *(const uint4*)(pb + 8);
    uint4 rb2 = *(const uint4*)(pb + 16), rb3 = *(const uint4*)(pb + 24);

    for (int k0 = 0; k0 < 1024; k0 += 64) {
        __syncthreads();
        *(uint4*)&As[srow * 72 + scol]      = ra0;
        *(uint4*)&As[srow * 72 + scol + 8]  = ra1;
        *(uint4*)&As[srow * 72 + scol + 16] = ra2;
        *(uint4*)&As[srow * 72 + scol + 24] = ra3;
        *(uint4*)&Bs[srow * 72 + scol]      = rb0;
        *(uint4*)&Bs[srow * 72 + scol + 8]  = rb1;
        *(uint4*)&Bs[srow * 72 + scol + 16] = rb2;
        *(uint4*)&Bs[srow * 72 + scol + 24] = rb3;
        __syncthreads();

        if (k0 < 960) {
            pa = A + (size_t)(row0 + srow) * 1024 + k0 + 64 + scol;
            pb = B + (size_t)(wofs + col0 + srow) * 1024 + k0 + 64 + scol;
            ra0 = *(const uint4*)(pa + 0);  ra1 = *(const uint4*)(pa + 8);
            ra2 = *(const uint4*)(pa + 16); ra3 = *(const uint4*)(pa + 24);
            rb0 = *(const uint4*)(pb + 0);  rb1 = *(const uint4*)(pb + 8);
            rb2 = *(const uint4*)(pb + 16); rb3 = *(const uint4*)(pb + 24);
        }

#pragma unroll
        for (int kk = 0; kk < 2; ++kk) {
            bf16x8 af[4], bfr[4];
#pragma unroll
            for (int m = 0; m < 4; ++m)
                af[m] = *(const bf16x8*)&As[(arow + m * 16) * 72 + kk * 32 + kof];
#pragma unroll
            for (int n = 0; n < 4; ++n)
                bfr[n] = *(const bf16x8*)&Bs[(brow + n * 16) * 72 + kk * 32 + kof];
#pragma unroll
            for (int m = 0; m < 4; ++m)
#pragma unroll
                for (int n = 0; n < 4; ++n)
                    acc[m][n] = __builtin_amdgcn_mfma_f32_16x16x32_bf16(af[m], bfr[n], acc[m][n], 0, 0, 0);
        }
    }

    const int ccol = lane & 15;
    const int crow = (lane >> 4) << 2;
#pragma unroll
    for (int n = 0; n < 4; ++n) {
        const int gc   = col0 + wc * 64 + n * 16 + ccol;
        const float bv = bias[wofs + gc];
        const int head = gc >> 6, d = gc & 63;
#pragma unroll
        for (int m = 0; m < 4; ++m) {
#pragma unroll
            for (int r = 0; r < 4; ++r) {
                const int gr = row0 + wr * 64 + m * 16 + crow + r;
                const int t  = gr >> 2, b = gr & 3;
                const int bh = (b << 4) + head;
                float vv = acc[m][n][r] + bv;
                if (z == 0)      Qb [((size_t)bh << 16) + ((size_t)t << 6) + d]  = f2bf(vv * QSCALE_F);
                else if (z == 1) Kb [((size_t)bh << 16) + ((size_t)t << 6) + d]  = f2bf(vv);
                else             Vtb[((size_t)bh << 16) + ((size_t)d << 10) + t] = f2bf(vv);
            }
        }
    }
}

// ===================== 2. flash attention (fixed-shift softmax, 2 s-tiles per barrier round) =====================
// 8 rounds x {barrier, stage A+B, barrier, prefetch, QK_A||QK_B, softmax/PV A, softmax/PV B}.
// Independent A/B chains give ILP; barrier count halved vs one-tile rounds.
__global__ __launch_bounds__(256)
void flash_kernel(const unsigned short* __restrict__ Qb, const unsigned short* __restrict__ Kb,
                  const unsigned short* __restrict__ Vtb, const float* __restrict__ attn_mask,
                  const int* __restrict__ padmask,
                  float* __restrict__ rl_buf, unsigned short* __restrict__ attn_out)
{
    const int j   = blockIdx.x;              // 0..1023
    const int xcd = j & 7, idx = j >> 3;     // idx 0..127
    const int bh  = xcd * 8 + (idx >> 4);
    const int t0  = (idx & 15) << 6;
    const int b   = bh >> 4, h = bh & 15;

    __shared__ __align__(16) unsigned short Ks[2][64 * 72];
    __shared__ __align__(16) unsigned short Vs[2][64 * 72];
    __shared__ __align__(16) unsigned short Ps[64 * 72];

    const int tid  = threadIdx.x;
    const int lane = tid & 63;
    const int wv   = tid >> 6;
    const int kof  = (lane >> 4) << 3;
    const int c16  = lane & 15;

    const unsigned short* Qbase = Qb  + ((size_t)bh << 16);
    const unsigned short* Kbase = Kb  + ((size_t)bh << 16);
    const unsigned short* Vbase = Vtb + ((size_t)bh << 16);

    bf16x8 qf[2];
#pragma unroll
    for (int kk = 0; kk < 2; ++kk)
        qf[kk] = *(const bf16x8*)(Qbase + ((size_t)(t0 + wv * 16 + c16) << 6) + kk * 32 + kof);

    const bf16x8 ones = {16256, 16256, 16256, 16256, 16256, 16256, 16256, 16256};

    const f32x4 zero4 = {0.f, 0.f, 0.f, 0.f};
    f32x4 acco[4];
#pragma unroll
    for (int nd = 0; nd < 4; ++nd) acco[nd] = zero4;
    f32x4 acc_l = zero4;

    const int srow_st = tid >> 2;            // 0..63
    const int scol_st = (tid & 3) << 4;      // 0,16,32,48

    const int rbase = wv * 16 + ((lane >> 4) << 2);
    const int tr    = t0 + rbase;

    // prologue: load tiles 0 (A) and 1 (B) into registers
    const unsigned short* kp = Kbase + ((size_t)srow_st << 6) + scol_st;
    const unsigned short* vp = Vbase + ((size_t)srow_st << 10) + scol_st;
    uint4 ka0 = *(const uint4*)kp,            ka1 = *(const uint4*)(kp + 8);
    uint4 kb0 = *(const uint4*)(kp + 4096),   kb1 = *(const uint4*)(kp + 4104); // +64 rows
    uint4 va0 = *(const uint4*)vp,            va1 = *(const uint4*)(vp + 8);
    uint4 vb0 = *(const uint4*)(vp + 64),     vb1 = *(const uint4*)(vp + 72);   // +64 cols

    for (int rd = 0; rd < 8; ++rd) {
        const int s0 = rd << 7;              // A at s0, B at s0+64
        __syncthreads();                     // previous round's LDS reads done
        *(uint4*)&Ks[0][srow_st * 72 + scol_st]     = ka0;
        *(uint4*)&Ks[0][srow_st * 72 + scol_st + 8] = ka1;
        *(uint4*)&Ks[1][srow_st * 72 + scol_st]     = kb0;
        *(uint4*)&Ks[1][srow_st * 72 + scol_st + 8] = kb1;
        *(uint4*)&Vs[0][srow_st * 72 + scol_st]     = va0;
        *(uint4*)&Vs[0][srow_st * 72 + scol_st + 8] = va1;
        *(uint4*)&Vs[1][srow_st * 72 + scol_st]     = vb0;
        *(uint4*)&Vs[1][srow_st * 72 + scol_st + 8] = vb1;
        __syncthreads();

        if (rd < 7) {                        // prefetch next round's two tiles
            const int sn = s0 + 128;
            kp = Kbase + ((size_t)(sn + srow_st) << 6) + scol_st;
            vp = Vbase + ((size_t)srow_st << 10) + sn + scol_st;
            ka0 = *(const uint4*)kp;          ka1 = *(const uint4*)(kp + 8);
            kb0 = *(const uint4*)(kp + 4096); kb1 = *(const uint4*)(kp + 4104);
            va0 = *(const uint4*)vp;          va1 = *(const uint4*)(vp + 8);
            vb0 = *(const uint4*)(vp + 64);   vb1 = *(const uint4*)(vp + 72);
        }

        // QK^T for both tiles (independent chains)
        f32x4 accsA[4], accsB[4];
#pragma unroll
        for (int n = 0; n < 4; ++n) { accsA[n] = zero4; accsB[n] = zero4; }
        __builtin_amdgcn_s_setprio(1);
#pragma unroll
        for (int n = 0; n < 4; ++n) {
            bf16x8 kfA0 = *(const bf16x8*)&Ks[0][(n * 16 + c16) * 72 + kof];
            bf16x8 kfA1 = *(const bf16x8*)&Ks[0][(n * 16 + c16) * 72 + 32 + kof];
            accsA[n] = __builtin_amdgcn_mfma_f32_16x16x32_bf16(qf[0], kfA0, accsA[n], 0, 0, 0);
            accsA[n] = __builtin_amdgcn_mfma_f32_16x16x32_bf16(qf[1], kfA1, accsA[n], 0, 0, 0);
            bf16x8 kfB0 = *(const bf16x8*)&Ks[1][(n * 16 + c16) * 72 + kof];
            bf16x8 kfB1 = *(const bf16x8*)&Ks[1][(n * 16 + c16) * 72 + 32 + kof];
            accsB[n] = __builtin_amdgcn_mfma_f32_16x16x32_bf16(qf[0], kfB0, accsB[n], 0, 0, 0);
            accsB[n] = __builtin_amdgcn_mfma_f32_16x16x32_bf16(qf[1], kfB1, accsB[n], 0, 0, 0);
        }
        __builtin_amdgcn_s_setprio(0);

        int padA[4], padB[4];
#pragma unroll
        for (int n = 0; n < 4; ++n) {
            padA[n] = padmask[(b << 10) + s0 + n * 16 + c16];
            padB[n] = padmask[(b << 10) + s0 + 64 + n * 16 + c16];
        }

        // ---- tile A: softmax -> Ps -> PV ----
#pragma unroll
        for (int r = 0; r < 4; ++r) {
            const float* mp = attn_mask + (size_t)(tr + r) * 1024 + s0 + c16;
            float x0 = fmaf(mp[ 0], LOG2E_F, accsA[0][r]);
            float x1 = fmaf(mp[16], LOG2E_F, accsA[1][r]);
            float x2 = fmaf(mp[32], LOG2E_F, accsA[2][r]);
            float x3 = fmaf(mp[48], LOG2E_F, accsA[3][r]);
            if (padA[0]) x0 = -1e30f;
            if (padA[1]) x1 = -1e30f;
            if (padA[2]) x2 = -1e30f;
            if (padA[3]) x3 = -1e30f;
            const int prow = rbase + r;
            Ps[prow * 72 +  0 + c16] = f2bfu(__builtin_amdgcn_exp2f(x0));
            Ps[prow * 72 + 16 + c16] = f2bfu(__builtin_amdgcn_exp2f(x1));
            Ps[prow * 72 + 32 + c16] = f2bfu(__builtin_amdgcn_exp2f(x2));
            Ps[prow * 72 + 48 + c16] = f2bfu(__builtin_amdgcn_exp2f(x3));
        }
        __builtin_amdgcn_s_setprio(1);
#pragma unroll
        for (int kk2 = 0; kk2 < 2; ++kk2) {
            bf16x8 pf = *(const bf16x8*)&Ps[(wv * 16 + c16) * 72 + kk2 * 32 + kof];
#pragma unroll
            for (int nd = 0; nd < 4; ++nd) {
                bf16x8 vf = *(const bf16x8*)&Vs[0][(nd * 16 + c16) * 72 + kk2 * 32 + kof];
                acco[nd] = __builtin_amdgcn_mfma_f32_16x16x32_bf16(pf, vf, acco[nd], 0, 0, 0);
            }
            acc_l = __builtin_amdgcn_mfma_f32_16x16x32_bf16(pf, ones, acc_l, 0, 0, 0);
        }
        __builtin_amdgcn_s_setprio(0);

        // ---- tile B: softmax -> Ps -> PV ----
#pragma unroll
        for (int r = 0; r < 4; ++r) {
            const float* mp = attn_mask + (size_t)(tr + r) * 1024 + s0 + 64 + c16;
            float x0 = fmaf(mp[ 0], LOG2E_F, accsB[0][r]);
            float x1 = fmaf(mp[16], LOG2E_F, accsB[1][r]);
            float x2 = fmaf(mp[32], LOG2E_F, accsB[2][r]);
            float x3 = fmaf(mp[48], LOG2E_F, accsB[3][r]);
            if (padB[0]) x0 = -1e30f;
            if (padB[1]) x1 = -1e30f;
            if (padB[2]) x2 = -1e30f;
            if (padB[3]) x3 = -1e30f;
            const int prow = rbase + r;
            Ps[prow * 72 +  0 + c16] = f2bfu(__builtin_amdgcn_exp2f(x0));
            Ps[prow * 72 + 16 + c16] = f2bfu(__builtin_amdgcn_exp2f(x1));
            Ps[prow * 72 + 32 + c16] = f2bfu(__builtin_amdgcn_exp2f(x2));
            Ps[prow * 72 + 48 + c16] = f2bfu(__builtin_amdgcn_exp2f(x3));
        }
        __builtin_amdgcn_s_setprio(1);
#pragma unroll
        for (int kk2 = 0; kk2 < 2; ++kk2) {
            bf16x8 pf = *(const bf16x8*)&Ps[(wv * 16 + c16) * 72 + kk2 * 32 + kof];
#pragma unroll
            for (int nd = 0; nd < 4; ++nd) {
                bf16x8 vf = *(const bf16x8*)&Vs[1][(nd * 16 + c16) * 72 + kk2 * 32 + kof];
                acco[nd] = __builtin_amdgcn_mfma_f32_16x16x32_bf16(pf, vf, acco[nd], 0, 0, 0);
            }
            acc_l = __builtin_amdgcn_mfma_f32_16x16x32_bf16(pf, ones, acc_l, 0, 0, 0);
        }
        __builtin_amdgcn_s_setprio(0);
    }

#pragma unroll
    for (int r = 0; r < 4; ++r) {
        const int t = t0 + rbase + r;
        const float rl = 1.0f / acc_l[r];
        if (c16 == 0)
            rl_buf[(bh << 10) + t] = rl;
#pragma unroll
        for (int nd = 0; nd < 4; ++nd) {
            const int d = nd * 16 + c16;
            attn_out[((size_t)t * 4 + b) * 1024 + h * 64 + d] = f2bf(acco[nd][r] * rl);
        }
    }
}

// ===================== 3. weights_avg (recompute scores, all heads) =====================
__global__ __launch_bounds__(256)
void wavg_kernel(const unsigned short* __restrict__ Qb, const unsigned short* __restrict__ Kb,
                 const float* __restrict__ attn_mask, const int* __restrict__ padmask,
                 const float* __restrict__ rl_buf, float* __restrict__ wout)
{
    const int j   = blockIdx.x;              // 0..1023
    const int xcd = j & 7;
    const int b   = xcd >> 1;
    const int rr  = ((j >> 3) << 1) + (xcd & 1);  // 0..255
    const int t0  = (rr >> 4) << 6;
    const int s0  = (rr & 15) << 6;

    __shared__ __align__(16) unsigned short Qs[64 * 72];
    __shared__ __align__(16) unsigned short Ks2[64 * 72];

    const int tid  = threadIdx.x;
    const int lane = tid & 63;
    const int wv   = tid >> 6;
    const int wr   = wv >> 1, wc = wv & 1;
    const int kof  = (lane >> 4) << 3;
    const int srow_st = tid >> 2;
    const int scol_st = (tid & 3) << 4;

    const int t_base = t0 + wr * 32 + ((lane >> 4) << 2);
    const int s_base = s0 + wc * 32 + (lane & 15);

    int pad2[2];
#pragma unroll
    for (int nn = 0; nn < 2; ++nn) pad2[nn] = padmask[(b << 10) + s_base + nn * 16];

    float maskv[2][2][4];
#pragma unroll
    for (int mm = 0; mm < 2; ++mm)
#pragma unroll
        for (int r = 0; r < 4; ++r)
#pragma unroll
            for (int nn = 0; nn < 2; ++nn)
                maskv[mm][nn][r] = attn_mask[(size_t)(t_base + mm * 16 + r) * 1024 + s_base + nn * 16] * LOG2E_F;

    float wsum[2][2][4];
#pragma unroll
    for (int mm = 0; mm < 2; ++mm)
#pragma unroll
        for (int nn = 0; nn < 2; ++nn)
#pragma unroll
            for (int r = 0; r < 4; ++r) wsum[mm][nn][r] = 0.f;

    for (int h = 0; h < 16; ++h) {
        const int bh = (b << 4) + h;
        __syncthreads();
        {
            const unsigned short* qp = Qb + ((size_t)bh << 16) + ((size_t)(t0 + srow_st) << 6) + scol_st;
            *(uint4*)&Qs[srow_st * 72 + scol_st]     = *(const uint4*)qp;
            *(uint4*)&Qs[srow_st * 72 + scol_st + 8] = *(const uint4*)(qp + 8);
            const unsigned short* kp = Kb + ((size_t)bh << 16) + ((size_t)(s0 + srow_st) << 6) + scol_st;
            *(uint4*)&Ks2[srow_st * 72 + scol_st]     = *(const uint4*)kp;
            *(uint4*)&Ks2[srow_st * 72 + scol_st + 8] = *(const uint4*)(kp + 8);
        }
        __syncthreads();

        float rlv[2][4];
#pragma unroll
        for (int mm = 0; mm < 2; ++mm)
#pragma unroll
            for (int r = 0; r < 4; ++r)
                rlv[mm][r] = rl_buf[(bh << 10) + t_base + mm * 16 + r];

        const f32x4 zero4 = {0.f, 0.f, 0.f, 0.f};
        f32x4 accs[2][2];
#pragma unroll
        for (int mm = 0; mm < 2; ++mm)
#pragma unroll
            for (int nn = 0; nn < 2; ++nn) accs[mm][nn] = zero4;
#pragma unroll
        for (int nn = 0; nn < 2; ++nn) {
            bf16x8 kf0 = *(const bf16x8*)&Ks2[(wc * 32 + nn * 16 + (lane & 15)) * 72 + kof];
            bf16x8 kf1 = *(const bf16x8*)&Ks2[(wc * 32 + nn * 16 + (lane & 15)) * 72 + 32 + kof];
#pragma unroll
            for (int mm = 0; mm < 2; ++mm) {
                bf16x8 qf0 = *(const bf16x8*)&Qs[(wr * 32 + mm * 16 + (lane & 15)) * 72 + kof];
                bf16x8 qf1 = *(const bf16x8*)&Qs[(wr * 32 + mm * 16 + (lane & 15)) * 72 + 32 + kof];
                accs[mm][nn] = __builtin_amdgcn_mfma_f32_16x16x32_bf16(qf0, kf0, accs[mm][nn], 0, 0, 0);
                accs[mm][nn] = __builtin_amdgcn_mfma_f32_16x16x32_bf16(qf1, kf1, accs[mm][nn], 0, 0, 0);
            }
        }
#pragma unroll
        for (int mm = 0; mm < 2; ++mm)
#pragma unroll
            for (int nn = 0; nn < 2; ++nn)
#pragma unroll
                for (int r = 0; r < 4; ++r)
                    if (!pad2[nn]) {
                        float x = accs[mm][nn][r] + maskv[mm][nn][r];
                        wsum[mm][nn][r] += __builtin_amdgcn_exp2f(x) * rlv[mm][r];
                    }
    }

#pragma unroll
    for (int mm = 0; mm < 2; ++mm)
#pragma unroll
        for (int nn = 0; nn < 2; ++nn)
#pragma unroll
            for (int r = 0; r < 4; ++r)
                wout[((size_t)b << 20) + (size_t)(t_base + mm * 16 + r) * 1024 + s_base + nn * 16]
                    = wsum[mm][nn][r] * 0.0625f;
}

// ===================== 4. out projection GEMM (bf16 A & W, BK=64, prefetch) =====================
__global__ __launch_bounds__(256)
void out_proj_kernel(const unsigned short* __restrict__ A, const unsigned short* __restrict__ Wb,
                     const float* __restrict__ bias, float* __restrict__ out)
{
    const int j   = blockIdx.x;           // 0..255
    const int xcd = j & 7, idx = j >> 3;
    const int row0 = ((xcd << 2) + (idx >> 3)) * 128;
    const int col0 = (idx & 7) * 128;

    __shared__ __align__(16) unsigned short As[128 * 72];
    __shared__ __align__(16) unsigned short Bs[128 * 72];

    const int tid  = threadIdx.x;
    const int lane = tid & 63;
    const int wv   = tid >> 6;
    const int wr   = wv >> 1, wc = wv & 1;

    const f32x4 zero4 = {0.f, 0.f, 0.f, 0.f};
    f32x4 acc[4][4];
#pragma unroll
    for (int m = 0; m < 4; ++m)
#pragma unroll
        for (int n = 0; n < 4; ++n) acc[m][n] = zero4;

    const int srow = tid >> 1;
    const int scol = (tid & 1) << 5;
    const int arow = wr * 64 + (lane & 15);
    const int brow = wc * 64 + (lane & 15);
    const int kof  = (lane >> 4) << 3;

    const unsigned short* pa = A  + (size_t)(row0 + srow) * 1024 + scol;
    const unsigned short* pb = Wb + (size_t)(col0 + srow) * 1024 + scol;
    uint4 ra0 = *(const uint4*)(pa + 0),  ra1 = *(const uint4*)(pa + 8);
    uint4 ra2 = *(const uint4*)(pa + 16), ra3 = *(const uint4*)(pa + 24);
    uint4 rb0 = *(const uint4*)(pb + 0),  rb1 = *(const uint4*)(pb + 8);
    uint4 rb2 = *(const uint4*)(pb + 16), rb3 = *(const uint4*)(pb + 24);

    for (int k0 = 0; k0 < 1024; k0 += 64) {
        __syncthreads();
        *(uint4*)&As[srow * 72 + scol]      = ra0;
        *(uint4*)&As[srow * 72 + scol + 8]  = ra1;
        *(uint4*)&As[srow * 72 + scol + 16] = ra2;
        *(uint4*)&As[srow * 72 + scol + 24] = ra3;
        *(uint4*)&Bs[srow * 72 + scol]      = rb0;
        *(uint4*)&Bs[srow * 72 + scol + 8]  = rb1;
        *(uint4*)&Bs[srow * 72 + scol + 16] = rb2;
        *(uint4*)&Bs[srow * 72 + scol + 24] = rb3;
        __syncthreads();

        if (k0 < 960) {
            pa = A  + (size_t)(row0 + srow) * 1024 + k0 + 64 + scol;
            pb = Wb + (size_t)(col0 + srow) * 1024 + k0 + 64 + scol;
            ra0 = *(const uint4*)(pa + 0);  ra1 = *(const uint4*)(pa + 8);
            ra2 = *(const uint4*)(pa + 16); ra3 = *(const uint4*)(pa + 24);
            rb0 = *(const uint4*)(pb + 0);  rb1 = *(const uint4*)(pb + 8);
            rb2 = *(const uint4*)(pb + 16); rb3 = *(const uint4*)(pb + 24);
        }

#pragma unroll
        for (int kk = 0; kk < 2; ++kk) {
            bf16x8 af[4], bfr[4];
#pragma unroll
            for (int m = 0; m < 4; ++m)
                af[m] = *(const bf16x8*)&As[(arow + m * 16) * 72 + kk * 32 + kof];
#pragma unroll
            for (int n = 0; n < 4; ++n)
                bfr[n] = *(const bf16x8*)&Bs[(brow + n * 16) * 72 + kk * 32 + kof];
#pragma unroll
            for (int m = 0; m < 4; ++m)
#pragma unroll
                for (int n = 0; n < 4; ++n)
                    acc[m][n] = __builtin_amdgcn_mfma_f32_16x16x32_bf16(af[m], bfr[n], acc[m][n], 0, 0, 0);
        }
    }

    const int ccol = lane & 15;
    const int crow = (lane >> 4) << 2;
#pragma unroll
    for (int n = 0; n < 4; ++n) {
        const int gc   = col0 + wc * 64 + n * 16 + ccol;
        const float bv = bias[gc];
#pragma unroll
        for (int m = 0; m < 4; ++m) {
#pragma unroll
            for (int r = 0; r < 4; ++r) {
                const int gr = row0 + wr * 64 + m * 16 + crow + r;
                out[(size_t)gr * 1024 + gc] = acc[m][n][r] + bv;
            }
        }
    }
}

// ===================== host =====================
extern "C" void kernel_launch(void* const* d_in, const int* in_sizes, int n_in,
                              void* d_out, int out_size, void* d_ws, size_t ws_size,
                              hipStream_t stream)
{
    const float* query     = (const float*)d_in[0];
    const float* key       = (const float*)d_in[1];
    const float* value     = (const float*)d_in[2];
    const float* attn_mask = (const float*)d_in[3];
    const int*   padmask   = (const int*)  d_in[4];
    const float* in_proj_w = (const float*)d_in[5];
    const float* in_proj_b = (const float*)d_in[6];
    const float* out_w     = (const float*)d_in[7];
    const float* out_b     = (const float*)d_in[8];

    float* out  = (float*)d_out;
    float* wavg = out + 4194304;

    char* ws = (char*)d_ws;
    unsigned short* Qb     = (unsigned short*)(ws);              // 8 MB  [64][1024][64]
    unsigned short* Kb     = (unsigned short*)(ws + 8388608);    // 8 MB
    unsigned short* Vtb    = (unsigned short*)(ws + 16777216);   // 8 MB  [64][64][1024]
    unsigned short* Xb     = (unsigned short*)(ws + 25165824);   // 24 MB (dead after qkv)
    unsigned short* attn_o = (unsigned short*)(ws + 25165824);   // 8 MB  aliases Xb
    unsigned short* Wb     = (unsigned short*)(ws + 50331648);   // 6 MB
    unsigned short* OWb    = (unsigned short*)(ws + 56623104);   // 2 MB
    float*          rl_buf = (float*)(ws + 58720256);            // 256 KB

    cvt_kernel<<<dim3(8192), 256, 0, stream>>>(query, key, value, in_proj_w, out_w,
                                               (uint4*)Xb, (uint4*)Wb, (uint4*)OWb);
    qkv_proj_kernel<<<dim3(256, 1, 3), 256, 0, stream>>>(Xb, Wb, in_proj_b, Qb, Kb, Vtb);
    flash_kernel<<<dim3(1024), 256, 0, stream>>>(Qb, Kb, Vtb, attn_mask, padmask,
                                                 rl_buf, attn_o);
    wavg_kernel<<<dim3(1024), 256, 0, stream>>>(Qb, Kb, attn_mask, padmask,
                                                rl_buf, wavg);
    out_proj_kernel<<<dim3(256), 256, 0, stream>>>(attn_o, OWb, out_b, out);
}

// Round 9
// 151.859 us; speedup vs baseline: 1.7889x; 1.0161x over previous
//
#include <hip/hip_runtime.h>
#include <stdint.h>

typedef short bf16x8 __attribute__((ext_vector_type(8)));
typedef float f32x4  __attribute__((ext_vector_type(4)));

#define LOG2E_F 1.4426950408889634f
// 0.125 * log2(e): folded into Q so exp2 args need no multiply
#define QSCALE_F 0.1803368801111204f

__device__ __forceinline__ unsigned short f2bf(float f) {
    unsigned int u = __float_as_uint(f);
    return (unsigned short)((u + 0x7FFFu + ((u >> 16) & 1u)) >> 16);
}

// fast pack for non-negative, non-NaN values (round-half-up)
__device__ __forceinline__ unsigned short f2bfu(float f) {
    return (unsigned short)((__float_as_uint(f) + 0x8000u) >> 16);
}

__device__ __forceinline__ uint4 pack8(float4 a, float4 b) {
    union { unsigned short us[8]; uint4 v; } p;
    p.us[0] = f2bf(a.x); p.us[1] = f2bf(a.y); p.us[2] = f2bf(a.z); p.us[3] = f2bf(a.w);
    p.us[4] = f2bf(b.x); p.us[5] = f2bf(b.y); p.us[6] = f2bf(b.z); p.us[7] = f2bf(b.w);
    return p.v;
}

// ===================== 0. f32 -> bf16 convert (X, in_proj_w, out_w) =====================
__global__ __launch_bounds__(256)
void cvt_kernel(const float* __restrict__ q, const float* __restrict__ k,
                const float* __restrict__ v, const float* __restrict__ w,
                const float* __restrict__ ow,
                uint4* __restrict__ Xb, uint4* __restrict__ Wb, uint4* __restrict__ OWb)
{
    const unsigned g = blockIdx.x * 256 + threadIdx.x;   // 0 .. 2097151
    const float* src;
    uint4* dst;
    if (g < 1572864u) {
        dst = Xb + g;
        if (g < 524288u)        src = q + (size_t)g * 8;
        else if (g < 1048576u)  src = k + (size_t)(g - 524288u) * 8;
        else                    src = v + (size_t)(g - 1048576u) * 8;
    } else if (g < 1966080u) {
        src = w + (size_t)(g - 1572864u) * 8;
        dst = Wb + (g - 1572864u);
    } else {
        src = ow + (size_t)(g - 1966080u) * 8;
        dst = OWb + (g - 1966080u);
    }
    float4 a = *(const float4*)src;
    float4 b = *(const float4*)(src + 4);
    *dst = pack8(a, b);
}

// ===================== 1. QKV projection GEMM (bf16 in, BK=64, prefetch) =====================
__global__ __launch_bounds__(256)
void qkv_proj_kernel(const unsigned short* __restrict__ Xb, const unsigned short* __restrict__ Wb,
                     const float* __restrict__ bias,
                     unsigned short* __restrict__ Qb, unsigned short* __restrict__ Kb,
                     unsigned short* __restrict__ Vtb)
{
    const int z = blockIdx.z;
    const int j   = blockIdx.x;           // 0..255
    const int xcd = j & 7, idx = j >> 3;  // idx 0..31
    const int row0 = ((xcd << 2) + (idx >> 3)) * 128;
    const int col0 = (idx & 7) * 128;
    const int wofs = z << 10;

    const unsigned short* A = Xb + (size_t)z * 4194304;
    const unsigned short* B = Wb;

    __shared__ __align__(16) unsigned short As[128 * 72];
    __shared__ __align__(16) unsigned short Bs[128 * 72];

    const int tid  = threadIdx.x;
    const int lane = tid & 63;
    const int wv   = tid >> 6;
    const int wr   = wv >> 1, wc = wv & 1;

    const f32x4 zero4 = {0.f, 0.f, 0.f, 0.f};
    f32x4 acc[4][4];
#pragma unroll
    for (int m = 0; m < 4; ++m)
#pragma unroll
        for (int n = 0; n < 4; ++n) acc[m][n] = zero4;

    const int srow = tid >> 1;
    const int scol = (tid & 1) << 5;
    const int arow = wr * 64 + (lane & 15);
    const int brow = wc * 64 + (lane & 15);
    const int kof  = (lane >> 4) << 3;

    const unsigned short* pa = A + (size_t)(row0 + srow) * 1024 + scol;
    const unsigned short* pb = B + (size_t)(wofs + col0 + srow) * 1024 + scol;
    uint4 ra0 = *(const uint4*)(pa + 0),  ra1 = *(const uint4*)(pa + 8);
    uint4 ra2 = *(const uint4*)(pa + 16), ra3 = *(const uint4*)(pa + 24);
    uint4 rb0 = *(const uint4*)(pb + 0),  rb1 = *(const uint4*)(pb + 8);
    uint4 rb2 = *(const uint4*)(pb + 16), rb3 = *(const uint4*)(pb + 24);

    for (int k0 = 0; k0 < 1024; k0 += 64) {
        __syncthreads();
        *(uint4*)&As[srow * 72 + scol]      = ra0;
        *(uint4*)&As[srow * 72 + scol + 8]  = ra1;
        *(uint4*)&As[srow * 72 + scol + 16] = ra2;
        *(uint4*)&As[srow * 72 + scol + 24] = ra3;
        *(uint4*)&Bs[srow * 72 + scol]      = rb0;
        *(uint4*)&Bs[srow * 72 + scol + 8]  = rb1;
        *(uint4*)&Bs[srow * 72 + scol + 16] = rb2;
        *(uint4*)&Bs[srow * 72 + scol + 24] = rb3;
        __syncthreads();

        if (k0 < 960) {
            pa = A + (size_t)(row0 + srow) * 1024 + k0 + 64 + scol;
            pb = B + (size_t)(wofs + col0 + srow) * 1024 + k0 + 64 + scol;
            ra0 = *(const uint4*)(pa + 0);  ra1 = *(const uint4*)(pa + 8);
            ra2 = *(const uint4*)(pa + 16); ra3 = *(const uint4*)(pa + 24);
            rb0 = *(const uint4*)(pb + 0);  rb1 = *(const uint4*)(pb + 8);
            rb2 = *(const uint4*)(pb + 16); rb3 = *(const uint4*)(pb + 24);
        }

#pragma unroll
        for (int kk = 0; kk < 2; ++kk) {
            bf16x8 af[4], bfr[4];
#pragma unroll
            for (int m = 0; m < 4; ++m)
                af[m] = *(const bf16x8*)&As[(arow + m * 16) * 72 + kk * 32 + kof];
#pragma unroll
            for (int n = 0; n < 4; ++n)
                bfr[n] = *(const bf16x8*)&Bs[(brow + n * 16) * 72 + kk * 32 + kof];
#pragma unroll
            for (int m = 0; m < 4; ++m)
#pragma unroll
                for (int n = 0; n < 4; ++n)
                    acc[m][n] = __builtin_amdgcn_mfma_f32_16x16x32_bf16(af[m], bfr[n], acc[m][n], 0, 0, 0);
        }
    }

    const int ccol = lane & 15;
    const int crow = (lane >> 4) << 2;
#pragma unroll
    for (int n = 0; n < 4; ++n) {
        const int gc   = col0 + wc * 64 + n * 16 + ccol;
        const float bv = bias[wofs + gc];
        const int head = gc >> 6, d = gc & 63;
#pragma unroll
        for (int m = 0; m < 4; ++m) {
#pragma unroll
            for (int r = 0; r < 4; ++r) {
                const int gr = row0 + wr * 64 + m * 16 + crow + r;
                const int t  = gr >> 2, b = gr & 3;
                const int bh = (b << 4) + head;
                float vv = acc[m][n][r] + bv;
                if (z == 0)      Qb [((size_t)bh << 16) + ((size_t)t << 6) + d]  = f2bf(vv * QSCALE_F);
                else if (z == 1) Kb [((size_t)bh << 16) + ((size_t)t << 6) + d]  = f2bf(vv);
                else             Vtb[((size_t)bh << 16) + ((size_t)d << 10) + t] = f2bf(vv);
            }
        }
    }
}

// ===================== 2. flash attention (fixed-shift softmax, 2 s-tiles/round, 8 waves) =====================
// 512 thr, 128 t-rows/block, grid 512 = exactly 2 blocks/CU (LDS 55.3 KB) -> 16 waves/CU, no tail.
__global__ __launch_bounds__(512)
void flash_kernel(const unsigned short* __restrict__ Qb, const unsigned short* __restrict__ Kb,
                  const unsigned short* __restrict__ Vtb, const float* __restrict__ attn_mask,
                  const int* __restrict__ padmask,
                  float* __restrict__ rl_buf, unsigned short* __restrict__ attn_out)
{
    const int j   = blockIdx.x;              // 0..511
    const int xcd = j & 7, idx = j >> 3;     // idx 0..63
    const int bh  = xcd * 8 + (idx >> 3);
    const int t0  = (idx & 7) << 7;
    const int b   = bh >> 4, h = bh & 15;

    __shared__ __align__(16) unsigned short Ks[2][64 * 72];
    __shared__ __align__(16) unsigned short Vs[2][64 * 72];
    __shared__ __align__(16) unsigned short Ps[128 * 72];

    const int tid  = threadIdx.x;
    const int lane = tid & 63;
    const int wv   = tid >> 6;               // 0..7
    const int kof  = (lane >> 4) << 3;
    const int c16  = lane & 15;

    const unsigned short* Qbase = Qb  + ((size_t)bh << 16);
    const unsigned short* Kbase = Kb  + ((size_t)bh << 16);
    const unsigned short* Vbase = Vtb + ((size_t)bh << 16);

    bf16x8 qf[2];
#pragma unroll
    for (int kk = 0; kk < 2; ++kk)
        qf[kk] = *(const bf16x8*)(Qbase + ((size_t)(t0 + wv * 16 + c16) << 6) + kk * 32 + kof);

    const bf16x8 ones = {16256, 16256, 16256, 16256, 16256, 16256, 16256, 16256};

    const f32x4 zero4 = {0.f, 0.f, 0.f, 0.f};
    f32x4 acco[4];
#pragma unroll
    for (int nd = 0; nd < 4; ++nd) acco[nd] = zero4;
    f32x4 acc_l = zero4;

    const int srow_st = tid >> 3;            // 0..63
    const int scol_st = (tid & 7) << 3;      // 0..56

    const int rbase = wv * 16 + ((lane >> 4) << 2);
    const int tr    = t0 + rbase;

    // prologue: load tiles 0 (A) and 1 (B) into registers (1 uint4 per tile per thread)
    const unsigned short* kp = Kbase + ((size_t)srow_st << 6) + scol_st;
    const unsigned short* vp = Vbase + ((size_t)srow_st << 10) + scol_st;
    uint4 ka = *(const uint4*)kp;
    uint4 kb = *(const uint4*)(kp + 4096);   // +64 rows
    uint4 va = *(const uint4*)vp;
    uint4 vb = *(const uint4*)(vp + 64);     // +64 cols

    for (int rd = 0; rd < 8; ++rd) {
        const int s0 = rd << 7;              // A at s0, B at s0+64
        __syncthreads();                     // previous round's LDS reads done
        *(uint4*)&Ks[0][srow_st * 72 + scol_st] = ka;
        *(uint4*)&Ks[1][srow_st * 72 + scol_st] = kb;
        *(uint4*)&Vs[0][srow_st * 72 + scol_st] = va;
        *(uint4*)&Vs[1][srow_st * 72 + scol_st] = vb;
        __syncthreads();

        if (rd < 7) {                        // prefetch next round's two tiles
            const int sn = s0 + 128;
            kp = Kbase + ((size_t)(sn + srow_st) << 6) + scol_st;
            vp = Vbase + ((size_t)srow_st << 10) + sn + scol_st;
            ka = *(const uint4*)kp;
            kb = *(const uint4*)(kp + 4096);
            va = *(const uint4*)vp;
            vb = *(const uint4*)(vp + 64);
        }

        // QK^T for both tiles (independent chains)
        f32x4 accsA[4], accsB[4];
#pragma unroll
        for (int n = 0; n < 4; ++n) { accsA[n] = zero4; accsB[n] = zero4; }
        __builtin_amdgcn_s_setprio(1);
#pragma unroll
        for (int n = 0; n < 4; ++n) {
            bf16x8 kfA0 = *(const bf16x8*)&Ks[0][(n * 16 + c16) * 72 + kof];
            bf16x8 kfA1 = *(const bf16x8*)&Ks[0][(n * 16 + c16) * 72 + 32 + kof];
            accsA[n] = __builtin_amdgcn_mfma_f32_16x16x32_bf16(qf[0], kfA0, accsA[n], 0, 0, 0);
            accsA[n] = __builtin_amdgcn_mfma_f32_16x16x32_bf16(qf[1], kfA1, accsA[n], 0, 0, 0);
            bf16x8 kfB0 = *(const bf16x8*)&Ks[1][(n * 16 + c16) * 72 + kof];
            bf16x8 kfB1 = *(const bf16x8*)&Ks[1][(n * 16 + c16) * 72 + 32 + kof];
            accsB[n] = __builtin_amdgcn_mfma_f32_16x16x32_bf16(qf[0], kfB0, accsB[n], 0, 0, 0);
            accsB[n] = __builtin_amdgcn_mfma_f32_16x16x32_bf16(qf[1], kfB1, accsB[n], 0, 0, 0);
        }
        __builtin_amdgcn_s_setprio(0);

        int padA[4], padB[4];
#pragma unroll
        for (int n = 0; n < 4; ++n) {
            padA[n] = padmask[(b << 10) + s0 + n * 16 + c16];
            padB[n] = padmask[(b << 10) + s0 + 64 + n * 16 + c16];
        }

        // ---- tile A: softmax -> Ps -> PV ----
#pragma unroll
        for (int r = 0; r < 4; ++r) {
            const float* mp = attn_mask + (size_t)(tr + r) * 1024 + s0 + c16;
            float x0 = fmaf(mp[ 0], LOG2E_F, accsA[0][r]);
            float x1 = fmaf(mp[16], LOG2E_F, accsA[1][r]);
            float x2 = fmaf(mp[32], LOG2E_F, accsA[2][r]);
            float x3 = fmaf(mp[48], LOG2E_F, accsA[3][r]);
            if (padA[0]) x0 = -1e30f;
            if (padA[1]) x1 = -1e30f;
            if (padA[2]) x2 = -1e30f;
            if (padA[3]) x3 = -1e30f;
            const int prow = rbase + r;
            Ps[prow * 72 +  0 + c16] = f2bfu(__builtin_amdgcn_exp2f(x0));
            Ps[prow * 72 + 16 + c16] = f2bfu(__builtin_amdgcn_exp2f(x1));
            Ps[prow * 72 + 32 + c16] = f2bfu(__builtin_amdgcn_exp2f(x2));
            Ps[prow * 72 + 48 + c16] = f2bfu(__builtin_amdgcn_exp2f(x3));
        }
        __builtin_amdgcn_s_setprio(1);
#pragma unroll
        for (int kk2 = 0; kk2 < 2; ++kk2) {
            bf16x8 pf = *(const bf16x8*)&Ps[(wv * 16 + c16) * 72 + kk2 * 32 + kof];
#pragma unroll
            for (int nd = 0; nd < 4; ++nd) {
                bf16x8 vf = *(const bf16x8*)&Vs[0][(nd * 16 + c16) * 72 + kk2 * 32 + kof];
                acco[nd] = __builtin_amdgcn_mfma_f32_16x16x32_bf16(pf, vf, acco[nd], 0, 0, 0);
            }
            acc_l = __builtin_amdgcn_mfma_f32_16x16x32_bf16(pf, ones, acc_l, 0, 0, 0);
        }
        __builtin_amdgcn_s_setprio(0);

        // ---- tile B: softmax -> Ps -> PV ----
#pragma unroll
        for (int r = 0; r < 4; ++r) {
            const float* mp = attn_mask + (size_t)(tr + r) * 1024 + s0 + 64 + c16;
            float x0 = fmaf(mp[ 0], LOG2E_F, accsB[0][r]);
            float x1 = fmaf(mp[16], LOG2E_F, accsB[1][r]);
            float x2 = fmaf(mp[32], LOG2E_F, accsB[2][r]);
            float x3 = fmaf(mp[48], LOG2E_F, accsB[3][r]);
            if (padB[0]) x0 = -1e30f;
            if (padB[1]) x1 = -1e30f;
            if (padB[2]) x2 = -1e30f;
            if (padB[3]) x3 = -1e30f;
            const int prow = rbase + r;
            Ps[prow * 72 +  0 + c16] = f2bfu(__builtin_amdgcn_exp2f(x0));
            Ps[prow * 72 + 16 + c16] = f2bfu(__builtin_amdgcn_exp2f(x1));
            Ps[prow * 72 + 32 + c16] = f2bfu(__builtin_amdgcn_exp2f(x2));
            Ps[prow * 72 + 48 + c16] = f2bfu(__builtin_amdgcn_exp2f(x3));
        }
        __builtin_amdgcn_s_setprio(1);
#pragma unroll
        for (int kk2 = 0; kk2 < 2; ++kk2) {
            bf16x8 pf = *(const bf16x8*)&Ps[(wv * 16 + c16) * 72 + kk2 * 32 + kof];
#pragma unroll
            for (int nd = 0; nd < 4; ++nd) {
                bf16x8 vf = *(const bf16x8*)&Vs[1][(nd * 16 + c16) * 72 + kk2 * 32 + kof];
                acco[nd] = __builtin_amdgcn_mfma_f32_16x16x32_bf16(pf, vf, acco[nd], 0, 0, 0);
            }
            acc_l = __builtin_amdgcn_mfma_f32_16x16x32_bf16(pf, ones, acc_l, 0, 0, 0);
        }
        __builtin_amdgcn_s_setprio(0);
    }

#pragma unroll
    for (int r = 0; r < 4; ++r) {
        const int t = t0 + rbase + r;
        const float rl = 1.0f / acc_l[r];
        if (c16 == 0)
            rl_buf[(bh << 10) + t] = rl;
#pragma unroll
        for (int nd = 0; nd < 4; ++nd) {
            const int d = nd * 16 + c16;
            attn_out[((size_t)t * 4 + b) * 1024 + h * 64 + d] = f2bf(acco[nd][r] * rl);
        }
    }
}

// ===================== 3. weights_avg (recompute scores, all heads) =====================
__global__ __launch_bounds__(256)
void wavg_kernel(const unsigned short* __restrict__ Qb, const unsigned short* __restrict__ Kb,
                 const float* __restrict__ attn_mask, const int* __restrict__ padmask,
                 const float* __restrict__ rl_buf, float* __restrict__ wout)
{
    const int j   = blockIdx.x;              // 0..1023
    const int xcd = j & 7;
    const int b   = xcd >> 1;
    const int rr  = ((j >> 3) << 1) + (xcd & 1);  // 0..255
    const int t0  = (rr >> 4) << 6;
    const int s0  = (rr & 15) << 6;

    __shared__ __align__(16) unsigned short Qs[64 * 72];
    __shared__ __align__(16) unsigned short Ks2[64 * 72];

    const int tid  = threadIdx.x;
    const int lane = tid & 63;
    const int wv   = tid >> 6;
    const int wr   = wv >> 1, wc = wv & 1;
    const int kof  = (lane >> 4) << 3;
    const int srow_st = tid >> 2;
    const int scol_st = (tid & 3) << 4;

    const int t_base = t0 + wr * 32 + ((lane >> 4) << 2);
    const int s_base = s0 + wc * 32 + (lane & 15);

    int pad2[2];
#pragma unroll
    for (int nn = 0; nn < 2; ++nn) pad2[nn] = padmask[(b << 10) + s_base + nn * 16];

    float maskv[2][2][4];
#pragma unroll
    for (int mm = 0; mm < 2; ++mm)
#pragma unroll
        for (int r = 0; r < 4; ++r)
#pragma unroll
            for (int nn = 0; nn < 2; ++nn)
                maskv[mm][nn][r] = attn_mask[(size_t)(t_base + mm * 16 + r) * 1024 + s_base + nn * 16] * LOG2E_F;

    float wsum[2][2][4];
#pragma unroll
    for (int mm = 0; mm < 2; ++mm)
#pragma unroll
        for (int nn = 0; nn < 2; ++nn)
#pragma unroll
            for (int r = 0; r < 4; ++r) wsum[mm][nn][r] = 0.f;

    for (int h = 0; h < 16; ++h) {
        const int bh = (b << 4) + h;
        __syncthreads();
        {
            const unsigned short* qp = Qb + ((size_t)bh << 16) + ((size_t)(t0 + srow_st) << 6) + scol_st;
            *(uint4*)&Qs[srow_st * 72 + scol_st]     = *(const uint4*)qp;
            *(uint4*)&Qs[srow_st * 72 + scol_st + 8] = *(const uint4*)(qp + 8);
            const unsigned short* kp = Kb + ((size_t)bh << 16) + ((size_t)(s0 + srow_st) << 6) + scol_st;
            *(uint4*)&Ks2[srow_st * 72 + scol_st]     = *(const uint4*)kp;
            *(uint4*)&Ks2[srow_st * 72 + scol_st + 8] = *(const uint4*)(kp + 8);
        }
        __syncthreads();

        float rlv[2][4];
#pragma unroll
        for (int mm = 0; mm < 2; ++mm)
#pragma unroll
            for (int r = 0; r < 4; ++r)
                rlv[mm][r] = rl_buf[(bh << 10) + t_base + mm * 16 + r];

        const f32x4 zero4 = {0.f, 0.f, 0.f, 0.f};
        f32x4 accs[2][2];
#pragma unroll
        for (int mm = 0; mm < 2; ++mm)
#pragma unroll
            for (int nn = 0; nn < 2; ++nn) accs[mm][nn] = zero4;
#pragma unroll
        for (int nn = 0; nn < 2; ++nn) {
            bf16x8 kf0 = *(const bf16x8*)&Ks2[(wc * 32 + nn * 16 + (lane & 15)) * 72 + kof];
            bf16x8 kf1 = *(const bf16x8*)&Ks2[(wc * 32 + nn * 16 + (lane & 15)) * 72 + 32 + kof];
#pragma unroll
            for (int mm = 0; mm < 2; ++mm) {
                bf16x8 qf0 = *(const bf16x8*)&Qs[(wr * 32 + mm * 16 + (lane & 15)) * 72 + kof];
                bf16x8 qf1 = *(const bf16x8*)&Qs[(wr * 32 + mm * 16 + (lane & 15)) * 72 + 32 + kof];
                accs[mm][nn] = __builtin_amdgcn_mfma_f32_16x16x32_bf16(qf0, kf0, accs[mm][nn], 0, 0, 0);
                accs[mm][nn] = __builtin_amdgcn_mfma_f32_16x16x32_bf16(qf1, kf1, accs[mm][nn], 0, 0, 0);
            }
        }
#pragma unroll
        for (int mm = 0; mm < 2; ++mm)
#pragma unroll
            for (int nn = 0; nn < 2; ++nn)
#pragma unroll
                for (int r = 0; r < 4; ++r)
                    if (!pad2[nn]) {
                        float x = accs[mm][nn][r] + maskv[mm][nn][r];
                        wsum[mm][nn][r] += __builtin_amdgcn_exp2f(x) * rlv[mm][r];
                    }
    }

#pragma unroll
    for (int mm = 0; mm < 2; ++mm)
#pragma unroll
        for (int nn = 0; nn < 2; ++nn)
#pragma unroll
            for (int r = 0; r < 4; ++r)
                wout[((size_t)b << 20) + (size_t)(t_base + mm * 16 + r) * 1024 + s_base + nn * 16]
                    = wsum[mm][nn][r] * 0.0625f;
}

// ===================== 4. out projection GEMM (bf16 A & W, BK=64, prefetch) =====================
__global__ __launch_bounds__(256)
void out_proj_kernel(const unsigned short* __restrict__ A, const unsigned short* __restrict__ Wb,
                     const float* __restrict__ bias, float* __restrict__ out)
{
    const int j   = blockIdx.x;           // 0..255
    const int xcd = j & 7, idx = j >> 3;
    const int row0 = ((xcd << 2) + (idx >> 3)) * 128;
    const int col0 = (idx & 7) * 128;

    __shared__ __align__(16) unsigned short As[128 * 72];
    __shared__ __align__(16) unsigned short Bs[128 * 72];

    const int tid  = threadIdx.x;
    const int lane = tid & 63;
    const int wv   = tid >> 6;
    const int wr   = wv >> 1, wc = wv & 1;

    const f32x4 zero4 = {0.f, 0.f, 0.f, 0.f};
    f32x4 acc[4][4];
#pragma unroll
    for (int m = 0; m < 4; ++m)
#pragma unroll
        for (int n = 0; n < 4; ++n) acc[m][n] = zero4;

    const int srow = tid >> 1;
    const int scol = (tid & 1) << 5;
    const int arow = wr * 64 + (lane & 15);
    const int brow = wc * 64 + (lane & 15);
    const int kof  = (lane >> 4) << 3;

    const unsigned short* pa = A  + (size_t)(row0 + srow) * 1024 + scol;
    const unsigned short* pb = Wb + (size_t)(col0 + srow) * 1024 + scol;
    uint4 ra0 = *(const uint4*)(pa + 0),  ra1 = *(const uint4*)(pa + 8);
    uint4 ra2 = *(const uint4*)(pa + 16), ra3 = *(const uint4*)(pa + 24);
    uint4 rb0 = *(const uint4*)(pb + 0),  rb1 = *(const uint4*)(pb + 8);
    uint4 rb2 = *(const uint4*)(pb + 16), rb3 = *(const uint4*)(pb + 24);

    for (int k0 = 0; k0 < 1024; k0 += 64) {
        __syncthreads();
        *(uint4*)&As[srow * 72 + scol]      = ra0;
        *(uint4*)&As[srow * 72 + scol + 8]  = ra1;
        *(uint4*)&As[srow * 72 + scol + 16] = ra2;
        *(uint4*)&As[srow * 72 + scol + 24] = ra3;
        *(uint4*)&Bs[srow * 72 + scol]      = rb0;
        *(uint4*)&Bs[srow * 72 + scol + 8]  = rb1;
        *(uint4*)&Bs[srow * 72 + scol + 16] = rb2;
        *(uint4*)&Bs[srow * 72 + scol + 24] = rb3;
        __syncthreads();

        if (k0 < 960) {
            pa = A  + (size_t)(row0 + srow) * 1024 + k0 + 64 + scol;
            pb = Wb + (size_t)(col0 + srow) * 1024 + k0 + 64 + scol;
            ra0 = *(const uint4*)(pa + 0);  ra1 = *(const uint4*)(pa + 8);
            ra2 = *(const uint4*)(pa + 16); ra3 = *(const uint4*)(pa + 24);
            rb0 = *(const uint4*)(pb + 0);  rb1 = *(const uint4*)(pb + 8);
            rb2 = *(const uint4*)(pb + 16); rb3 = *(const uint4*)(pb + 24);
        }

#pragma unroll
        for (int kk = 0; kk < 2; ++kk) {
            bf16x8 af[4], bfr[4];
#pragma unroll
            for (int m = 0; m < 4; ++m)
                af[m] = *(const bf16x8*)&As[(arow + m * 16) * 72 + kk * 32 + kof];
#pragma unroll
            for (int n = 0; n < 4; ++n)
                bfr[n] = *(const bf16x8*)&Bs[(brow + n * 16) * 72 + kk * 32 + kof];
#pragma unroll
            for (int m = 0; m < 4; ++m)
#pragma unroll
                for (int n = 0; n < 4; ++n)
                    acc[m][n] = __builtin_amdgcn_mfma_f32_16x16x32_bf16(af[m], bfr[n], acc[m][n], 0, 0, 0);
        }
    }

    const int ccol = lane & 15;
    const int crow = (lane >> 4) << 2;
#pragma unroll
    for (int n = 0; n < 4; ++n) {
        const int gc   = col0 + wc * 64 + n * 16 + ccol;
        const float bv = bias[gc];
#pragma unroll
        for (int m = 0; m < 4; ++m) {
#pragma unroll
            for (int r = 0; r < 4; ++r) {
                const int gr = row0 + wr * 64 + m * 16 + crow + r;
                out[(size_t)gr * 1024 + gc] = acc[m][n][r] + bv;
            }
        }
    }
}

// ===================== host =====================
extern "C" void kernel_launch(void* const* d_in, const int* in_sizes, int n_in,
                              void* d_out, int out_size, void* d_ws, size_t ws_size,
                              hipStream_t stream)
{
    const float* query     = (const float*)d_in[0];
    const float* key       = (const float*)d_in[1];
    const float* value     = (const float*)d_in[2];
    const float* attn_mask = (const float*)d_in[3];
    const int*   padmask   = (const int*)  d_in[4];
    const float* in_proj_w = (const float*)d_in[5];
    const float* in_proj_b = (const float*)d_in[6];
    const float* out_w     = (const float*)d_in[7];
    const float* out_b     = (const float*)d_in[8];

    float* out  = (float*)d_out;
    float* wavg = out + 4194304;

    char* ws = (char*)d_ws;
    unsigned short* Qb     = (unsigned short*)(ws);              // 8 MB  [64][1024][64]
    unsigned short* Kb     = (unsigned short*)(ws + 8388608);    // 8 MB
    unsigned short* Vtb    = (unsigned short*)(ws + 16777216);   // 8 MB  [64][64][1024]
    unsigned short* Xb     = (unsigned short*)(ws + 25165824);   // 24 MB (dead after qkv)
    unsigned short* attn_o = (unsigned short*)(ws + 25165824);   // 8 MB  aliases Xb
    unsigned short* Wb     = (unsigned short*)(ws + 50331648);   // 6 MB
    unsigned short* OWb    = (unsigned short*)(ws + 56623104);   // 2 MB
    float*          rl_buf = (float*)(ws + 58720256);            // 256 KB

    cvt_kernel<<<dim3(8192), 256, 0, stream>>>(query, key, value, in_proj_w, out_w,
                                               (uint4*)Xb, (uint4*)Wb, (uint4*)OWb);
    qkv_proj_kernel<<<dim3(256, 1, 3), 256, 0, stream>>>(Xb, Wb, in_proj_b, Qb, Kb, Vtb);
    flash_kernel<<<dim3(512), 512, 0, stream>>>(Qb, Kb, Vtb, attn_mask, padmask,
                                                rl_buf, attn_o);
    wavg_kernel<<<dim3(1024), 256, 0, stream>>>(Qb, Kb, attn_mask, padmask,
                                                rl_buf, wavg);
    out_proj_kernel<<<dim3(256), 256, 0, stream>>>(attn_o, OWb, out_b, out);
}

// Round 10
// 151.151 us; speedup vs baseline: 1.7973x; 1.0047x over previous
//
#include <hip/hip_runtime.h>
#include <stdint.h>

typedef short bf16x8 __attribute__((ext_vector_type(8)));
typedef float f32x4  __attribute__((ext_vector_type(4)));

#define LOG2E_F 1.4426950408889634f
// 0.125 * log2(e): folded into Q so exp2 args need no multiply
#define QSCALE_F 0.1803368801111204f

__device__ __forceinline__ unsigned short f2bf(float f) {
    unsigned int u = __float_as_uint(f);
    return (unsigned short)((u + 0x7FFFu + ((u >> 16) & 1u)) >> 16);
}

// fast pack for non-negative, non-NaN values (round-half-up)
__device__ __forceinline__ unsigned short f2bfu(float f) {
    return (unsigned short)((__float_as_uint(f) + 0x8000u) >> 16);
}

__device__ __forceinline__ uint4 pack8(float4 a, float4 b) {
    union { unsigned short us[8]; uint4 v; } p;
    p.us[0] = f2bf(a.x); p.us[1] = f2bf(a.y); p.us[2] = f2bf(a.z); p.us[3] = f2bf(a.w);
    p.us[4] = f2bf(b.x); p.us[5] = f2bf(b.y); p.us[6] = f2bf(b.z); p.us[7] = f2bf(b.w);
    return p.v;
}

// ===================== 0. f32 -> bf16 convert (X, in_proj_w, out_w) =====================
__global__ __launch_bounds__(256)
void cvt_kernel(const float* __restrict__ q, const float* __restrict__ k,
                const float* __restrict__ v, const float* __restrict__ w,
                const float* __restrict__ ow,
                uint4* __restrict__ Xb, uint4* __restrict__ Wb, uint4* __restrict__ OWb)
{
    const unsigned g = blockIdx.x * 256 + threadIdx.x;   // 0 .. 2097151
    const float* src;
    uint4* dst;
    if (g < 1572864u) {
        dst = Xb + g;
        if (g < 524288u)        src = q + (size_t)g * 8;
        else if (g < 1048576u)  src = k + (size_t)(g - 524288u) * 8;
        else                    src = v + (size_t)(g - 1048576u) * 8;
    } else if (g < 1966080u) {
        src = w + (size_t)(g - 1572864u) * 8;
        dst = Wb + (g - 1572864u);
    } else {
        src = ow + (size_t)(g - 1966080u) * 8;
        dst = OWb + (g - 1966080u);
    }
    float4 a = *(const float4*)src;
    float4 b = *(const float4*)(src + 4);
    *dst = pack8(a, b);
}

// ===================== 1. QKV projection GEMM (bf16 in, BK=64, prefetch) =====================
__global__ __launch_bounds__(256)
void qkv_proj_kernel(const unsigned short* __restrict__ Xb, const unsigned short* __restrict__ Wb,
                     const float* __restrict__ bias,
                     unsigned short* __restrict__ Qb, unsigned short* __restrict__ Kb,
                     unsigned short* __restrict__ Vtb)
{
    const int z = blockIdx.z;
    const int j   = blockIdx.x;           // 0..255
    const int xcd = j & 7, idx = j >> 3;  // idx 0..31
    const int row0 = ((xcd << 2) + (idx >> 3)) * 128;
    const int col0 = (idx & 7) * 128;
    const int wofs = z << 10;

    const unsigned short* A = Xb + (size_t)z * 4194304;
    const unsigned short* B = Wb;

    __shared__ __align__(16) unsigned short As[128 * 72];
    __shared__ __align__(16) unsigned short Bs[128 * 72];

    const int tid  = threadIdx.x;
    const int lane = tid & 63;
    const int wv   = tid >> 6;
    const int wr   = wv >> 1, wc = wv & 1;

    const f32x4 zero4 = {0.f, 0.f, 0.f, 0.f};
    f32x4 acc[4][4];
#pragma unroll
    for (int m = 0; m < 4; ++m)
#pragma unroll
        for (int n = 0; n < 4; ++n) acc[m][n] = zero4;

    const int srow = tid >> 1;
    const int scol = (tid & 1) << 5;
    const int arow = wr * 64 + (lane & 15);
    const int brow = wc * 64 + (lane & 15);
    const int kof  = (lane >> 4) << 3;

    const unsigned short* pa = A + (size_t)(row0 + srow) * 1024 + scol;
    const unsigned short* pb = B + (size_t)(wofs + col0 + srow) * 1024 + scol;
    uint4 ra0 = *(const uint4*)(pa + 0),  ra1 = *(const uint4*)(pa + 8);
    uint4 ra2 = *(const uint4*)(pa + 16), ra3 = *(const uint4*)(pa + 24);
    uint4 rb0 = *(const uint4*)(pb + 0),  rb1 = *(const uint4*)(pb + 8);
    uint4 rb2 = *(const uint4*)(pb + 16), rb3 = *(const uint4*)(pb + 24);

    for (int k0 = 0; k0 < 1024; k0 += 64) {
        __syncthreads();
        *(uint4*)&As[srow * 72 + scol]      = ra0;
        *(uint4*)&As[srow * 72 + scol + 8]  = ra1;
        *(uint4*)&As[srow * 72 + scol + 16] = ra2;
        *(uint4*)&As[srow * 72 + scol + 24] = ra3;
        *(uint4*)&Bs[srow * 72 + scol]      = rb0;
        *(uint4*)&Bs[srow * 72 + scol + 8]  = rb1;
        *(uint4*)&Bs[srow * 72 + scol + 16] = rb2;
        *(uint4*)&Bs[srow * 72 + scol + 24] = rb3;
        __syncthreads();

        if (k0 < 960) {
            pa = A + (size_t)(row0 + srow) * 1024 + k0 + 64 + scol;
            pb = B + (size_t)(wofs + col0 + srow) * 1024 + k0 + 64 + scol;
            ra0 = *(const uint4*)(pa + 0);  ra1 = *(const uint4*)(pa + 8);
            ra2 = *(const uint4*)(pa + 16); ra3 = *(const uint4*)(pa + 24);
            rb0 = *(const uint4*)(pb + 0);  rb1 = *(const uint4*)(pb + 8);
            rb2 = *(const uint4*)(pb + 16); rb3 = *(const uint4*)(pb + 24);
        }

#pragma unroll
        for (int kk = 0; kk < 2; ++kk) {
            bf16x8 af[4], bfr[4];
#pragma unroll
            for (int m = 0; m < 4; ++m)
                af[m] = *(const bf16x8*)&As[(arow + m * 16) * 72 + kk * 32 + kof];
#pragma unroll
            for (int n = 0; n < 4; ++n)
                bfr[n] = *(const bf16x8*)&Bs[(brow + n * 16) * 72 + kk * 32 + kof];
#pragma unroll
            for (int m = 0; m < 4; ++m)
#pragma unroll
                for (int n = 0; n < 4; ++n)
                    acc[m][n] = __builtin_amdgcn_mfma_f32_16x16x32_bf16(af[m], bfr[n], acc[m][n], 0, 0, 0);
        }
    }

    const int ccol = lane & 15;
    const int crow = (lane >> 4) << 2;
#pragma unroll
    for (int n = 0; n < 4; ++n) {
        const int gc   = col0 + wc * 64 + n * 16 + ccol;
        const float bv = bias[wofs + gc];
        const int head = gc >> 6, d = gc & 63;
#pragma unroll
        for (int m = 0; m < 4; ++m) {
#pragma unroll
            for (int r = 0; r < 4; ++r) {
                const int gr = row0 + wr * 64 + m * 16 + crow + r;
                const int t  = gr >> 2, b = gr & 3;
                const int bh = (b << 4) + head;
                float vv = acc[m][n][r] + bv;
                if (z == 0)      Qb [((size_t)bh << 16) + ((size_t)t << 6) + d]  = f2bf(vv * QSCALE_F);
                else if (z == 1) Kb [((size_t)bh << 16) + ((size_t)t << 6) + d]  = f2bf(vv);
                else             Vtb[((size_t)bh << 16) + ((size_t)d << 10) + t] = f2bf(vv);
            }
        }
    }
}

// ===================== 2. flash attention (fixed-shift softmax, cross-round dbuf, 1 barrier/round) =====================
// 512 thr, 128 t-rows, grid 512. K/V 4 tile-buffers: round rd reads buf[rd&1] (written last round),
// writes buf[rd&1 ^1] right after the barrier. Single __syncthreads per round; drains are covered.
__global__ __launch_bounds__(512)
void flash_kernel(const unsigned short* __restrict__ Qb, const unsigned short* __restrict__ Kb,
                  const unsigned short* __restrict__ Vtb, const float* __restrict__ attn_mask,
                  const int* __restrict__ padmask,
                  float* __restrict__ rl_buf, unsigned short* __restrict__ attn_out)
{
    const int j   = blockIdx.x;              // 0..511
    const int xcd = j & 7, idx = j >> 3;     // idx 0..63
    const int bh  = xcd * 8 + (idx >> 3);
    const int t0  = (idx & 7) << 7;
    const int b   = bh >> 4, h = bh & 15;

    __shared__ __align__(16) unsigned short Ks[2][2][64 * 72];  // [dbuf][tile]
    __shared__ __align__(16) unsigned short Vs[2][2][64 * 72];
    __shared__ __align__(16) unsigned short Ps[128 * 72];

    const int tid  = threadIdx.x;
    const int lane = tid & 63;
    const int wv   = tid >> 6;               // 0..7
    const int kof  = (lane >> 4) << 3;
    const int c16  = lane & 15;

    const unsigned short* Qbase = Qb  + ((size_t)bh << 16);
    const unsigned short* Kbase = Kb  + ((size_t)bh << 16);
    const unsigned short* Vbase = Vtb + ((size_t)bh << 16);

    bf16x8 qf[2];
#pragma unroll
    for (int kk = 0; kk < 2; ++kk)
        qf[kk] = *(const bf16x8*)(Qbase + ((size_t)(t0 + wv * 16 + c16) << 6) + kk * 32 + kof);

    const bf16x8 ones = {16256, 16256, 16256, 16256, 16256, 16256, 16256, 16256};

    const f32x4 zero4 = {0.f, 0.f, 0.f, 0.f};
    f32x4 acco[4];
#pragma unroll
    for (int nd = 0; nd < 4; ++nd) acco[nd] = zero4;
    f32x4 acc_l = zero4;

    const int srow_st = tid >> 3;            // 0..63
    const int scol_st = (tid & 7) << 3;      // 0..56

    const int rbase = wv * 16 + ((lane >> 4) << 2);
    const int tr    = t0 + rbase;

    // ---- prologue: load round0 (tiles 0,1), stage into buf0, load round1 regs ----
    const unsigned short* kp = Kbase + ((size_t)srow_st << 6) + scol_st;
    const unsigned short* vp = Vbase + ((size_t)srow_st << 10) + scol_st;
    uint4 kA = *(const uint4*)kp;
    uint4 kB = *(const uint4*)(kp + 4096);   // +64 s-rows
    uint4 vA = *(const uint4*)vp;
    uint4 vB = *(const uint4*)(vp + 64);     // +64 s-cols

    *(uint4*)&Ks[0][0][srow_st * 72 + scol_st] = kA;
    *(uint4*)&Ks[0][1][srow_st * 72 + scol_st] = kB;
    *(uint4*)&Vs[0][0][srow_st * 72 + scol_st] = vA;
    *(uint4*)&Vs[0][1][srow_st * 72 + scol_st] = vB;

    kp = Kbase + ((size_t)(128 + srow_st) << 6) + scol_st;
    vp = Vbase + ((size_t)srow_st << 10) + 128 + scol_st;
    kA = *(const uint4*)kp;
    kB = *(const uint4*)(kp + 4096);
    vA = *(const uint4*)vp;
    vB = *(const uint4*)(vp + 64);
    __syncthreads();

    for (int rd = 0; rd < 8; ++rd) {
        const int cur = rd & 1;
        const int s0  = rd << 7;             // A at s0, B at s0+64

        if (rd < 7) {
            // stage round rd+1 (regs loaded last round) into the other buffer.
            // Safe: barrier at end of round rd-1 ensured all waves finished reading it.
            *(uint4*)&Ks[cur ^ 1][0][srow_st * 72 + scol_st] = kA;
            *(uint4*)&Ks[cur ^ 1][1][srow_st * 72 + scol_st] = kB;
            *(uint4*)&Vs[cur ^ 1][0][srow_st * 72 + scol_st] = vA;
            *(uint4*)&Vs[cur ^ 1][1][srow_st * 72 + scol_st] = vB;
        }
        if (rd < 6) {
            // issue loads for round rd+2; full round of compute to cover latency
            const int sn = s0 + 256;
            kp = Kbase + ((size_t)(sn + srow_st) << 6) + scol_st;
            vp = Vbase + ((size_t)srow_st << 10) + sn + scol_st;
            kA = *(const uint4*)kp;
            kB = *(const uint4*)(kp + 4096);
            vA = *(const uint4*)vp;
            vB = *(const uint4*)(vp + 64);
        }

        int padA[4], padB[4];
#pragma unroll
        for (int n = 0; n < 4; ++n) {
            padA[n] = padmask[(b << 10) + s0 + n * 16 + c16];
            padB[n] = padmask[(b << 10) + s0 + 64 + n * 16 + c16];
        }

        // QK^T for both tiles (independent chains) from buf[cur] (already resident)
        f32x4 accsA[4], accsB[4];
#pragma unroll
        for (int n = 0; n < 4; ++n) { accsA[n] = zero4; accsB[n] = zero4; }
        __builtin_amdgcn_s_setprio(1);
#pragma unroll
        for (int n = 0; n < 4; ++n) {
            bf16x8 kfA0 = *(const bf16x8*)&Ks[cur][0][(n * 16 + c16) * 72 + kof];
            bf16x8 kfA1 = *(const bf16x8*)&Ks[cur][0][(n * 16 + c16) * 72 + 32 + kof];
            accsA[n] = __builtin_amdgcn_mfma_f32_16x16x32_bf16(qf[0], kfA0, accsA[n], 0, 0, 0);
            accsA[n] = __builtin_amdgcn_mfma_f32_16x16x32_bf16(qf[1], kfA1, accsA[n], 0, 0, 0);
            bf16x8 kfB0 = *(const bf16x8*)&Ks[cur][1][(n * 16 + c16) * 72 + kof];
            bf16x8 kfB1 = *(const bf16x8*)&Ks[cur][1][(n * 16 + c16) * 72 + 32 + kof];
            accsB[n] = __builtin_amdgcn_mfma_f32_16x16x32_bf16(qf[0], kfB0, accsB[n], 0, 0, 0);
            accsB[n] = __builtin_amdgcn_mfma_f32_16x16x32_bf16(qf[1], kfB1, accsB[n], 0, 0, 0);
        }
        __builtin_amdgcn_s_setprio(0);

        // ---- tile A: softmax -> Ps -> PV ----
#pragma unroll
        for (int r = 0; r < 4; ++r) {
            const float* mp = attn_mask + (size_t)(tr + r) * 1024 + s0 + c16;
            float x0 = fmaf(mp[ 0], LOG2E_F, accsA[0][r]);
            float x1 = fmaf(mp[16], LOG2E_F, accsA[1][r]);
            float x2 = fmaf(mp[32], LOG2E_F, accsA[2][r]);
            float x3 = fmaf(mp[48], LOG2E_F, accsA[3][r]);
            if (padA[0]) x0 = -1e30f;
            if (padA[1]) x1 = -1e30f;
            if (padA[2]) x2 = -1e30f;
            if (padA[3]) x3 = -1e30f;
            const int prow = rbase + r;
            Ps[prow * 72 +  0 + c16] = f2bfu(__builtin_amdgcn_exp2f(x0));
            Ps[prow * 72 + 16 + c16] = f2bfu(__builtin_amdgcn_exp2f(x1));
            Ps[prow * 72 + 32 + c16] = f2bfu(__builtin_amdgcn_exp2f(x2));
            Ps[prow * 72 + 48 + c16] = f2bfu(__builtin_amdgcn_exp2f(x3));
        }
        __builtin_amdgcn_s_setprio(1);
#pragma unroll
        for (int kk2 = 0; kk2 < 2; ++kk2) {
            bf16x8 pf = *(const bf16x8*)&Ps[(wv * 16 + c16) * 72 + kk2 * 32 + kof];
#pragma unroll
            for (int nd = 0; nd < 4; ++nd) {
                bf16x8 vf = *(const bf16x8*)&Vs[cur][0][(nd * 16 + c16) * 72 + kk2 * 32 + kof];
                acco[nd] = __builtin_amdgcn_mfma_f32_16x16x32_bf16(pf, vf, acco[nd], 0, 0, 0);
            }
            acc_l = __builtin_amdgcn_mfma_f32_16x16x32_bf16(pf, ones, acc_l, 0, 0, 0);
        }
        __builtin_amdgcn_s_setprio(0);

        // ---- tile B: softmax -> Ps -> PV ----
#pragma unroll
        for (int r = 0; r < 4; ++r) {
            const float* mp = attn_mask + (size_t)(tr + r) * 1024 + s0 + 64 + c16;
            float x0 = fmaf(mp[ 0], LOG2E_F, accsB[0][r]);
            float x1 = fmaf(mp[16], LOG2E_F, accsB[1][r]);
            float x2 = fmaf(mp[32], LOG2E_F, accsB[2][r]);
            float x3 = fmaf(mp[48], LOG2E_F, accsB[3][r]);
            if (padB[0]) x0 = -1e30f;
            if (padB[1]) x1 = -1e30f;
            if (padB[2]) x2 = -1e30f;
            if (padB[3]) x3 = -1e30f;
            const int prow = rbase + r;
            Ps[prow * 72 +  0 + c16] = f2bfu(__builtin_amdgcn_exp2f(x0));
            Ps[prow * 72 + 16 + c16] = f2bfu(__builtin_amdgcn_exp2f(x1));
            Ps[prow * 72 + 32 + c16] = f2bfu(__builtin_amdgcn_exp2f(x2));
            Ps[prow * 72 + 48 + c16] = f2bfu(__builtin_amdgcn_exp2f(x3));
        }
        __builtin_amdgcn_s_setprio(1);
#pragma unroll
        for (int kk2 = 0; kk2 < 2; ++kk2) {
            bf16x8 pf = *(const bf16x8*)&Ps[(wv * 16 + c16) * 72 + kk2 * 32 + kof];
#pragma unroll
            for (int nd = 0; nd < 4; ++nd) {
                bf16x8 vf = *(const bf16x8*)&Vs[cur][1][(nd * 16 + c16) * 72 + kk2 * 32 + kof];
                acco[nd] = __builtin_amdgcn_mfma_f32_16x16x32_bf16(pf, vf, acco[nd], 0, 0, 0);
            }
            acc_l = __builtin_amdgcn_mfma_f32_16x16x32_bf16(pf, ones, acc_l, 0, 0, 0);
        }
        __builtin_amdgcn_s_setprio(0);

        if (rd < 7) __syncthreads();
    }

#pragma unroll
    for (int r = 0; r < 4; ++r) {
        const int t = t0 + rbase + r;
        const float rl = 1.0f / acc_l[r];
        if (c16 == 0)
            rl_buf[(bh << 10) + t] = rl;
#pragma unroll
        for (int nd = 0; nd < 4; ++nd) {
            const int d = nd * 16 + c16;
            attn_out[((size_t)t * 4 + b) * 1024 + h * 64 + d] = f2bf(acco[nd][r] * rl);
        }
    }
}

// ===================== 3. weights_avg (recompute, 1-barrier h-pipeline) =====================
__global__ __launch_bounds__(256)
void wavg_kernel(const unsigned short* __restrict__ Qb, const unsigned short* __restrict__ Kb,
                 const float* __restrict__ attn_mask, const int* __restrict__ padmask,
                 const float* __restrict__ rl_buf, float* __restrict__ wout)
{
    const int j   = blockIdx.x;              // 0..1023
    const int xcd = j & 7;
    const int b   = xcd >> 1;
    const int rr  = ((j >> 3) << 1) + (xcd & 1);  // 0..255
    const int t0  = (rr >> 4) << 6;
    const int s0  = (rr & 15) << 6;

    __shared__ __align__(16) unsigned short Qs[2][64 * 72];
    __shared__ __align__(16) unsigned short Ks2[2][64 * 72];

    const int tid  = threadIdx.x;
    const int lane = tid & 63;
    const int wv   = tid >> 6;
    const int wr   = wv >> 1, wc = wv & 1;
    const int kof  = (lane >> 4) << 3;
    const int srow_st = tid >> 2;
    const int scol_st = (tid & 3) << 4;

    const int t_base = t0 + wr * 32 + ((lane >> 4) << 2);
    const int s_base = s0 + wc * 32 + (lane & 15);

    int pad2[2];
#pragma unroll
    for (int nn = 0; nn < 2; ++nn) pad2[nn] = padmask[(b << 10) + s_base + nn * 16];

    float maskv[2][2][4];
#pragma unroll
    for (int mm = 0; mm < 2; ++mm)
#pragma unroll
        for (int r = 0; r < 4; ++r)
#pragma unroll
            for (int nn = 0; nn < 2; ++nn)
                maskv[mm][nn][r] = attn_mask[(size_t)(t_base + mm * 16 + r) * 1024 + s_base + nn * 16] * LOG2E_F;

    float wsum[2][2][4];
#pragma unroll
    for (int mm = 0; mm < 2; ++mm)
#pragma unroll
        for (int nn = 0; nn < 2; ++nn)
#pragma unroll
            for (int r = 0; r < 4; ++r) wsum[mm][nn][r] = 0.f;

    const unsigned short* qsrc = Qb + ((size_t)(t0 + srow_st) << 6) + scol_st;
    const unsigned short* ksrc = Kb + ((size_t)(s0 + srow_st) << 6) + scol_st;
    const size_t bh0 = (size_t)(b << 4) << 16;

    // prologue: load h0 regs, stage, load h1 regs
    uint4 q0 = *(const uint4*)(qsrc + bh0);
    uint4 q1 = *(const uint4*)(qsrc + bh0 + 8);
    uint4 k0 = *(const uint4*)(ksrc + bh0);
    uint4 k1 = *(const uint4*)(ksrc + bh0 + 8);
    *(uint4*)&Qs[0][srow_st * 72 + scol_st]      = q0;
    *(uint4*)&Qs[0][srow_st * 72 + scol_st + 8]  = q1;
    *(uint4*)&Ks2[0][srow_st * 72 + scol_st]     = k0;
    *(uint4*)&Ks2[0][srow_st * 72 + scol_st + 8] = k1;
    q0 = *(const uint4*)(qsrc + bh0 + 65536);
    q1 = *(const uint4*)(qsrc + bh0 + 65536 + 8);
    k0 = *(const uint4*)(ksrc + bh0 + 65536);
    k1 = *(const uint4*)(ksrc + bh0 + 65536 + 8);
    __syncthreads();

#pragma unroll 2
    for (int h = 0; h < 16; ++h) {
        const int cur = h & 1;
        const int bh  = (b << 4) + h;

        if (h < 15) {
            *(uint4*)&Qs[cur ^ 1][srow_st * 72 + scol_st]      = q0;
            *(uint4*)&Qs[cur ^ 1][srow_st * 72 + scol_st + 8]  = q1;
            *(uint4*)&Ks2[cur ^ 1][srow_st * 72 + scol_st]     = k0;
            *(uint4*)&Ks2[cur ^ 1][srow_st * 72 + scol_st + 8] = k1;
        }
        if (h < 14) {
            const size_t of = bh0 + (size_t)(h + 2) * 65536;
            q0 = *(const uint4*)(qsrc + of);
            q1 = *(const uint4*)(qsrc + of + 8);
            k0 = *(const uint4*)(ksrc + of);
            k1 = *(const uint4*)(ksrc + of + 8);
        }

        float rlv[2][4];
#pragma unroll
        for (int mm = 0; mm < 2; ++mm)
#pragma unroll
            for (int r = 0; r < 4; ++r)
                rlv[mm][r] = rl_buf[(bh << 10) + t_base + mm * 16 + r];

        const f32x4 zero4 = {0.f, 0.f, 0.f, 0.f};
        f32x4 accs[2][2];
#pragma unroll
        for (int mm = 0; mm < 2; ++mm)
#pragma unroll
            for (int nn = 0; nn < 2; ++nn) accs[mm][nn] = zero4;
#pragma unroll
        for (int nn = 0; nn < 2; ++nn) {
            bf16x8 kf0 = *(const bf16x8*)&Ks2[cur][(wc * 32 + nn * 16 + (lane & 15)) * 72 + kof];
            bf16x8 kf1 = *(const bf16x8*)&Ks2[cur][(wc * 32 + nn * 16 + (lane & 15)) * 72 + 32 + kof];
#pragma unroll
            for (int mm = 0; mm < 2; ++mm) {
                bf16x8 qf0 = *(const bf16x8*)&Qs[cur][(wr * 32 + mm * 16 + (lane & 15)) * 72 + kof];
                bf16x8 qf1 = *(const bf16x8*)&Qs[cur][(wr * 32 + mm * 16 + (lane & 15)) * 72 + 32 + kof];
                accs[mm][nn] = __builtin_amdgcn_mfma_f32_16x16x32_bf16(qf0, kf0, accs[mm][nn], 0, 0, 0);
                accs[mm][nn] = __builtin_amdgcn_mfma_f32_16x16x32_bf16(qf1, kf1, accs[mm][nn], 0, 0, 0);
            }
        }
#pragma unroll
        for (int mm = 0; mm < 2; ++mm)
#pragma unroll
            for (int nn = 0; nn < 2; ++nn)
#pragma unroll
                for (int r = 0; r < 4; ++r)
                    if (!pad2[nn]) {
                        float x = accs[mm][nn][r] + maskv[mm][nn][r];
                        wsum[mm][nn][r] += __builtin_amdgcn_exp2f(x) * rlv[mm][r];
                    }

        if (h < 15) __syncthreads();
    }

#pragma unroll
    for (int mm = 0; mm < 2; ++mm)
#pragma unroll
        for (int nn = 0; nn < 2; ++nn)
#pragma unroll
            for (int r = 0; r < 4; ++r)
                wout[((size_t)b << 20) + (size_t)(t_base + mm * 16 + r) * 1024 + s_base + nn * 16]
                    = wsum[mm][nn][r] * 0.0625f;
}

// ===================== 4. out projection GEMM (bf16 A & W, BK=64, prefetch) =====================
__global__ __launch_bounds__(256)
void out_proj_kernel(const unsigned short* __restrict__ A, const unsigned short* __restrict__ Wb,
                     const float* __restrict__ bias, float* __restrict__ out)
{
    const int j   = blockIdx.x;           // 0..255
    const int xcd = j & 7, idx = j >> 3;
    const int row0 = ((xcd << 2) + (idx >> 3)) * 128;
    const int col0 = (idx & 7) * 128;

    __shared__ __align__(16) unsigned short As[128 * 72];
    __shared__ __align__(16) unsigned short Bs[128 * 72];

    const int tid  = threadIdx.x;
    const int lane = tid & 63;
    const int wv   = tid >> 6;
    const int wr   = wv >> 1, wc = wv & 1;

    const f32x4 zero4 = {0.f, 0.f, 0.f, 0.f};
    f32x4 acc[4][4];
#pragma unroll
    for (int m = 0; m < 4; ++m)
#pragma unroll
        for (int n = 0; n < 4; ++n) acc[m][n] = zero4;

    const int srow = tid >> 1;
    const int scol = (tid & 1) << 5;
    const int arow = wr * 64 + (lane & 15);
    const int brow = wc * 64 + (lane & 15);
    const int kof  = (lane >> 4) << 3;

    const unsigned short* pa = A  + (size_t)(row0 + srow) * 1024 + scol;
    const unsigned short* pb = Wb + (size_t)(col0 + srow) * 1024 + scol;
    uint4 ra0 = *(const uint4*)(pa + 0),  ra1 = *(const uint4*)(pa + 8);
    uint4 ra2 = *(const uint4*)(pa + 16), ra3 = *(const uint4*)(pa + 24);
    uint4 rb0 = *(const uint4*)(pb + 0),  rb1 = *(const uint4*)(pb + 8);
    uint4 rb2 = *(const uint4*)(pb + 16), rb3 = *(const uint4*)(pb + 24);

    for (int k0 = 0; k0 < 1024; k0 += 64) {
        __syncthreads();
        *(uint4*)&As[srow * 72 + scol]      = ra0;
        *(uint4*)&As[srow * 72 + scol + 8]  = ra1;
        *(uint4*)&As[srow * 72 + scol + 16] = ra2;
        *(uint4*)&As[srow * 72 + scol + 24] = ra3;
        *(uint4*)&Bs[srow * 72 + scol]      = rb0;
        *(uint4*)&Bs[srow * 72 + scol + 8]  = rb1;
        *(uint4*)&Bs[srow * 72 + scol + 16] = rb2;
        *(uint4*)&Bs[srow * 72 + scol + 24] = rb3;
        __syncthreads();

        if (k0 < 960) {
            pa = A  + (size_t)(row0 + srow) * 1024 + k0 + 64 + scol;
            pb = Wb + (size_t)(col0 + srow) * 1024 + k0 + 64 + scol;
            ra0 = *(const uint4*)(pa + 0);  ra1 = *(const uint4*)(pa + 8);
            ra2 = *(const uint4*)(pa + 16); ra3 = *(const uint4*)(pa + 24);
            rb0 = *(const uint4*)(pb + 0);  rb1 = *(const uint4*)(pb + 8);
            rb2 = *(const uint4*)(pb + 16); rb3 = *(const uint4*)(pb + 24);
        }

#pragma unroll
        for (int kk = 0; kk < 2; ++kk) {
            bf16x8 af[4], bfr[4];
#pragma unroll
            for (int m = 0; m < 4; ++m)
                af[m] = *(const bf16x8*)&As[(arow + m * 16) * 72 + kk * 32 + kof];
#pragma unroll
            for (int n = 0; n < 4; ++n)
                bfr[n] = *(const bf16x8*)&Bs[(brow + n * 16) * 72 + kk * 32 + kof];
#pragma unroll
            for (int m = 0; m < 4; ++m)
#pragma unroll
                for (int n = 0; n < 4; ++n)
                    acc[m][n] = __builtin_amdgcn_mfma_f32_16x16x32_bf16(af[m], bfr[n], acc[m][n], 0, 0, 0);
        }
    }

    const int ccol = lane & 15;
    const int crow = (lane >> 4) << 2;
#pragma unroll
    for (int n = 0; n < 4; ++n) {
        const int gc   = col0 + wc * 64 + n * 16 + ccol;
        const float bv = bias[gc];
#pragma unroll
        for (int m = 0; m < 4; ++m) {
#pragma unroll
            for (int r = 0; r < 4; ++r) {
                const int gr = row0 + wr * 64 + m * 16 + crow + r;
                out[(size_t)gr * 1024 + gc] = acc[m][n][r] + bv;
            }
        }
    }
}

// ===================== host =====================
extern "C" void kernel_launch(void* const* d_in, const int* in_sizes, int n_in,
                              void* d_out, int out_size, void* d_ws, size_t ws_size,
                              hipStream_t stream)
{
    const float* query     = (const float*)d_in[0];
    const float* key       = (const float*)d_in[1];
    const float* value     = (const float*)d_in[2];
    const float* attn_mask = (const float*)d_in[3];
    const int*   padmask   = (const int*)  d_in[4];
    const float* in_proj_w = (const float*)d_in[5];
    const float* in_proj_b = (const float*)d_in[6];
    const float* out_w     = (const float*)d_in[7];
    const float* out_b     = (const float*)d_in[8];

    float* out  = (float*)d_out;
    float* wavg = out + 4194304;

    char* ws = (char*)d_ws;
    unsigned short* Qb     = (unsigned short*)(ws);              // 8 MB  [64][1024][64]
    unsigned short* Kb     = (unsigned short*)(ws + 8388608);    // 8 MB
    unsigned short* Vtb    = (unsigned short*)(ws + 16777216);   // 8 MB  [64][64][1024]
    unsigned short* Xb     = (unsigned short*)(ws + 25165824);   // 24 MB (dead after qkv)
    unsigned short* attn_o = (unsigned short*)(ws + 25165824);   // 8 MB  aliases Xb
    unsigned short* Wb     = (unsigned short*)(ws + 50331648);   // 6 MB
    unsigned short* OWb    = (unsigned short*)(ws + 56623104);   // 2 MB
    float*          rl_buf = (float*)(ws + 58720256);            // 256 KB

    cvt_kernel<<<dim3(8192), 256, 0, stream>>>(query, key, value, in_proj_w, out_w,
                                               (uint4*)Xb, (uint4*)Wb, (uint4*)OWb);
    qkv_proj_kernel<<<dim3(256, 1, 3), 256, 0, stream>>>(Xb, Wb, in_proj_b, Qb, Kb, Vtb);
    flash_kernel<<<dim3(512), 512, 0, stream>>>(Qb, Kb, Vtb, attn_mask, padmask,
                                                rl_buf, attn_o);
    wavg_kernel<<<dim3(1024), 256, 0, stream>>>(Qb, Kb, attn_mask, padmask,
                                                rl_buf, wavg);
    out_proj_kernel<<<dim3(256), 256, 0, stream>>>(attn_o, OWb, out_b, out);
}